// Round 1
// baseline (3788.393 us; speedup 1.0000x reference)
//
#include <hip/hip_runtime.h>
#include <hip/hip_bf16.h>
#include <math.h>

#define NHEADS 20

// ---------------- generic fp32 GEMM: C[M,N] = A[M,K] @ B[K,N] ----------------
// 64x64 tile, BK=16, 256 threads, 4x4 per thread. M%64==0, N%64==0, K%16==0,
// lda/ldb/ldc multiples of 4 (float4 loads/stores).
__global__ __launch_bounds__(256) void gemm_f32(
    const float* __restrict__ A, const float* __restrict__ B, float* __restrict__ C,
    int M, int N, int K, int lda, int ldb, int ldc) {
  __shared__ float As[16][68];
  __shared__ float Bs[16][68];
  const int t = threadIdx.x;
  const int bm = blockIdx.y * 64;
  const int bn = blockIdx.x * 64;
  const int tx = t & 15, ty = t >> 4;
  float acc[4][4];
  #pragma unroll
  for (int i = 0; i < 4; ++i)
    #pragma unroll
    for (int j = 0; j < 4; ++j) acc[i][j] = 0.f;

  const int am = t >> 2, akq = (t & 3) << 2;   // A: thread loads float4 at (am, akq)
  const int bk = t >> 4, bn4 = (t & 15) << 2;  // B: thread loads float4 at (bk, bn4)

  for (int k0 = 0; k0 < K; k0 += 16) {
    float4 av = *reinterpret_cast<const float4*>(&A[(size_t)(bm + am) * lda + k0 + akq]);
    float4 bv = *reinterpret_cast<const float4*>(&B[(size_t)(k0 + bk) * ldb + bn + bn4]);
    As[akq + 0][am] = av.x;
    As[akq + 1][am] = av.y;
    As[akq + 2][am] = av.z;
    As[akq + 3][am] = av.w;
    *reinterpret_cast<float4*>(&Bs[bk][bn4]) = bv;
    __syncthreads();
    #pragma unroll
    for (int kk = 0; kk < 16; ++kk) {
      float4 a4 = *reinterpret_cast<const float4*>(&As[kk][ty << 2]);
      float4 b4 = *reinterpret_cast<const float4*>(&Bs[kk][tx << 2]);
      float af[4] = {a4.x, a4.y, a4.z, a4.w};
      float bf[4] = {b4.x, b4.y, b4.z, b4.w};
      #pragma unroll
      for (int i = 0; i < 4; ++i)
        #pragma unroll
        for (int j = 0; j < 4; ++j)
          acc[i][j] = fmaf(af[i], bf[j], acc[i][j]);
    }
    __syncthreads();
  }
  #pragma unroll
  for (int i = 0; i < 4; ++i) {
    float4 cv = make_float4(acc[i][0], acc[i][1], acc[i][2], acc[i][3]);
    *reinterpret_cast<float4*>(&C[(size_t)(bm + ty * 4 + i) * ldc + bn + tx * 4]) = cv;
  }
}

// ---------------- row-wise RMSNorm: out = in * rsqrt(mean(in^2)+eps) * g ----
__global__ __launch_bounds__(256) void rmsnorm_kernel(
    const float* __restrict__ in, const float* __restrict__ g, float* __restrict__ out,
    int N, int in_stride, int out_stride) {
  __shared__ float red[256];
  const int row = blockIdx.x, t = threadIdx.x;
  const float* x = in + (size_t)row * in_stride;
  float s = 0.f;
  for (int i = t; i < N; i += 256) { float v = x[i]; s += v * v; }
  red[t] = s;
  __syncthreads();
  for (int o = 128; o > 0; o >>= 1) {
    if (t < o) red[t] += red[t + o];
    __syncthreads();
  }
  const float scale = rsqrtf(red[0] / (float)N + 1e-6f);
  float* y = out + (size_t)row * out_stride;
  for (int i = t; i < N; i += 256) y[i] = x[i] * scale * g[i];
}

// ---------------- RoPE: q rope slices in place; ckv[...,512:576] -> kr ------
__global__ __launch_bounds__(256) void rope_kernel(
    float* __restrict__ q, const float* __restrict__ ckv, float* __restrict__ kr) {
  const int s = blockIdx.x;
  const int t = threadIdx.x;
  const float fs = (float)s;
  for (int pi = t; pi < NHEADS * 32 + 32; pi += 256) {
    int i = pi & 31;
    // inv_freq[i] = theta^(-2i/64) = 1e6^(-i/32)
    float ang = fs * powf(1.0e6f, -(float)i * (1.f / 32.f));
    float c = cosf(ang), sn = sinf(ang);
    if (pi < NHEADS * 32) {
      int h = pi >> 5;
      float* ptr = q + (size_t)s * 5120 + h * 256 + 192;
      float x0 = ptr[i], x1 = ptr[i + 32];
      ptr[i] = x0 * c - x1 * sn;
      ptr[i + 32] = x1 * c + x0 * sn;
    } else {
      float x0 = ckv[(size_t)s * 576 + 512 + i];
      float x1 = ckv[(size_t)s * 576 + 512 + 32 + i];
      kr[(size_t)s * 64 + i] = x0 * c - x1 * sn;
      kr[(size_t)s * 64 + 32 + i] = x1 * c + x0 * sn;
    }
  }
}

// ---------------- flash attention, causal, fp32 -----------------------------
// grid (S/32, NHEADS), 256 threads. Thread t: row r=t>>3 (of 32 q-rows),
// part p=t&7 owning dims d = j*32 + p*4 + i (j<8, i<4).
__global__ __launch_bounds__(256) void flash_attn(
    const float* __restrict__ q, const float* __restrict__ kv,
    const float* __restrict__ kr, float* __restrict__ outp) {
  __shared__ float qs[32][260];
  __shared__ float ks[32][260];   // K tile, then reused as V tile
  __shared__ float sc[32][33];
  __shared__ float row_m[32], row_l[32], row_rs[32];
  const int t = threadIdx.x;
  const int qt = blockIdx.x;
  const int h = blockIdx.y;
  const int r = t >> 3;
  const int p = t & 7;

  for (int idx = t; idx < 32 * 256; idx += 256) {
    int row = idx >> 8, col = idx & 255;
    qs[row][col] = q[(size_t)(qt * 32 + row) * 5120 + h * 256 + col];
  }
  if (t < 32) { row_m[t] = -INFINITY; row_l[t] = 0.f; }
  float acc[8][4];
  #pragma unroll
  for (int j = 0; j < 8; ++j)
    #pragma unroll
    for (int i = 0; i < 4; ++i) acc[j][i] = 0.f;

  for (int kt = 0; kt <= qt; ++kt) {
    __syncthreads();  // prev PV done (and Q/init done on first iter)
    // K tile: cols 0..191 = k_nope from kv, cols 192..255 = roped k_rope
    for (int idx = t; idx < 32 * 256; idx += 256) {
      int row = idx >> 8, col = idx & 255;
      float v;
      if (col < 192) v = kv[(size_t)(kt * 32 + row) * 8960 + h * 448 + col];
      else           v = kr[(size_t)(kt * 32 + row) * 64 + (col - 192)];
      ks[row][col] = v;
    }
    __syncthreads();
    // scores: thread computes sc[r][c] for c = i*8+p, i<4
    float dot[4] = {0.f, 0.f, 0.f, 0.f};
    for (int d = 0; d < 256; d += 4) {
      float4 qa = *reinterpret_cast<const float4*>(&qs[r][d]);
      #pragma unroll
      for (int i = 0; i < 4; ++i) {
        float4 kb = *reinterpret_cast<const float4*>(&ks[i * 8 + p][d]);
        dot[i] += qa.x * kb.x + qa.y * kb.y + qa.z * kb.z + qa.w * kb.w;
      }
    }
    const int qpos = qt * 32 + r;
    #pragma unroll
    for (int i = 0; i < 4; ++i) {
      int c = i * 8 + p;
      int kpos = kt * 32 + c;
      sc[r][c] = (kpos <= qpos) ? dot[i] * 0.0625f : -INFINITY;
    }
    __syncthreads();
    // online softmax (leaders) concurrent with V load (nobody reads ks now)
    if (t < 32) {
      float m_old = row_m[t];
      float tm = -INFINITY;
      #pragma unroll
      for (int c = 0; c < 32; ++c) tm = fmaxf(tm, sc[t][c]);
      float nm = fmaxf(m_old, tm);
      float rs = expf(m_old - nm);
      float lsum = 0.f;
      #pragma unroll
      for (int c = 0; c < 32; ++c) {
        float e = expf(sc[t][c] - nm);
        sc[t][c] = e;
        lsum += e;
      }
      row_m[t] = nm;
      row_l[t] = row_l[t] * rs + lsum;
      row_rs[t] = rs;
    }
    for (int idx = t; idx < 32 * 256; idx += 256) {
      int row = idx >> 8, col = idx & 255;
      ks[row][col] = kv[(size_t)(kt * 32 + row) * 8960 + h * 448 + 192 + col];
    }
    __syncthreads();
    // rescale + PV accumulate
    float rs = row_rs[r];
    #pragma unroll
    for (int j = 0; j < 8; ++j)
      #pragma unroll
      for (int i = 0; i < 4; ++i) acc[j][i] *= rs;
    for (int c = 0; c < 32; ++c) {
      float w = sc[r][c];
      #pragma unroll
      for (int j = 0; j < 8; ++j) {
        float4 v4 = *reinterpret_cast<const float4*>(&ks[c][(j << 5) + (p << 2)]);
        acc[j][0] = fmaf(w, v4.x, acc[j][0]);
        acc[j][1] = fmaf(w, v4.y, acc[j][1]);
        acc[j][2] = fmaf(w, v4.z, acc[j][2]);
        acc[j][3] = fmaf(w, v4.w, acc[j][3]);
      }
    }
  }
  const float inv_l = 1.f / row_l[r];
  #pragma unroll
  for (int j = 0; j < 8; ++j) {
    float4 ov = make_float4(acc[j][0] * inv_l, acc[j][1] * inv_l,
                            acc[j][2] * inv_l, acc[j][3] * inv_l);
    *reinterpret_cast<float4*>(
        &outp[(size_t)(qt * 32 + r) * 5120 + h * 256 + (j << 5) + (p << 2)]) = ov;
  }
}

extern "C" void kernel_launch(void* const* d_in, const int* in_sizes, int n_in,
                              void* d_out, int out_size, void* d_ws, size_t ws_size,
                              hipStream_t stream) {
  const float* hidden = (const float*)d_in[0];  // [2048, 2048]
  const float* w_q_a  = (const float*)d_in[1];  // [2048, 768]
  const float* w_q_b  = (const float*)d_in[2];  // [768, 5120]
  const float* w_kv_a = (const float*)d_in[3];  // [2048, 576]
  const float* w_kv_b = (const float*)d_in[4];  // [512, 8960]
  const float* w_o    = (const float*)d_in[5];  // [5120, 2048]
  const float* g_q_a  = (const float*)d_in[6];  // [768]
  const float* g_kv_a = (const float*)d_in[7];  // [512]
  float* out = (float*)d_out;                   // [2048, 2048]

  const int S = 2048;
  float* ws = (float*)d_ws;
  float* q    = ws;                               // [S, 5120]
  float* kv   = q  + (size_t)S * 5120;            // [S, 8960]
  float* kr   = kv + (size_t)S * 8960;            // [S, 64]
  float* tmp  = kr + (size_t)S * 64;              // [S, 5120] region (aliased)
  float* q_a  = tmp;                              // [S, 768]
  float* ckv  = tmp + (size_t)S * 768;            // [S, 576]
  float* kv_c = ckv + (size_t)S * 576;            // [S, 512]
  float* attn = tmp;                              // [S, 5120] (q_a/ckv/kv_c dead by then)

  dim3 blk(256);

  // q_a = hidden @ w_q_a ; q_c = rmsnorm(q_a) (in place)
  gemm_f32<<<dim3(768 / 64, S / 64), blk, 0, stream>>>(hidden, w_q_a, q_a,
                                                       S, 768, 2048, 2048, 768, 768);
  rmsnorm_kernel<<<S, blk, 0, stream>>>(q_a, g_q_a, q_a, 768, 768, 768);
  // q = q_c @ w_q_b
  gemm_f32<<<dim3(5120 / 64, S / 64), blk, 0, stream>>>(q_a, w_q_b, q,
                                                        S, 5120, 768, 768, 5120, 5120);
  // ckv = hidden @ w_kv_a ; kv_c = rmsnorm(ckv[:, :512])
  gemm_f32<<<dim3(576 / 64, S / 64), blk, 0, stream>>>(hidden, w_kv_a, ckv,
                                                       S, 576, 2048, 2048, 576, 576);
  rmsnorm_kernel<<<S, blk, 0, stream>>>(ckv, g_kv_a, kv_c, 512, 576, 512);
  // kv = kv_c @ w_kv_b
  gemm_f32<<<dim3(8960 / 64, S / 64), blk, 0, stream>>>(kv_c, w_kv_b, kv,
                                                        S, 8960, 512, 512, 8960, 8960);
  // RoPE on q (in place) and ckv rope cols -> kr
  rope_kernel<<<S, blk, 0, stream>>>(q, ckv, kr);
  // attention
  flash_attn<<<dim3(S / 32, NHEADS), blk, 0, stream>>>(q, kv, kr, attn);
  // out = attn @ w_o
  gemm_f32<<<dim3(2048 / 64, S / 64), blk, 0, stream>>>(attn, w_o, out,
                                                        S, 2048, 5120, 5120, 2048, 2048);
}

// Round 2
// 1563.600 us; speedup vs baseline: 2.4229x; 2.4229x over previous
//
#include <hip/hip_runtime.h>
#include <hip/hip_bf16.h>
#include <math.h>

#define NHEADS 20

typedef short bf16x8 __attribute__((ext_vector_type(8)));
typedef float f32x4 __attribute__((ext_vector_type(4)));

__device__ inline float bf2f(unsigned short u) {
  union { unsigned int i; float f; } x; x.i = ((unsigned int)u) << 16; return x.f;
}
__device__ inline unsigned short f2bf(float f) {
  __hip_bfloat16 h = __float2bfloat16(f);
  union { __hip_bfloat16 h; unsigned short u; } x; x.h = h; return x.u;
}

// ---------------- generic fp32 GEMM: C[M,N] = A[M,K] @ B[K,N] ----------------
__global__ __launch_bounds__(256) void gemm_f32(
    const float* __restrict__ A, const float* __restrict__ B, float* __restrict__ C,
    int M, int N, int K, int lda, int ldb, int ldc) {
  __shared__ float As[16][68];
  __shared__ float Bs[16][68];
  const int t = threadIdx.x;
  const int bm = blockIdx.y * 64;
  const int bn = blockIdx.x * 64;
  const int tx = t & 15, ty = t >> 4;
  float acc[4][4];
  #pragma unroll
  for (int i = 0; i < 4; ++i)
    #pragma unroll
    for (int j = 0; j < 4; ++j) acc[i][j] = 0.f;

  const int am = t >> 2, akq = (t & 3) << 2;
  const int bk = t >> 4, bn4 = (t & 15) << 2;

  for (int k0 = 0; k0 < K; k0 += 16) {
    float4 av = *reinterpret_cast<const float4*>(&A[(size_t)(bm + am) * lda + k0 + akq]);
    float4 bv = *reinterpret_cast<const float4*>(&B[(size_t)(k0 + bk) * ldb + bn + bn4]);
    As[akq + 0][am] = av.x;
    As[akq + 1][am] = av.y;
    As[akq + 2][am] = av.z;
    As[akq + 3][am] = av.w;
    *reinterpret_cast<float4*>(&Bs[bk][bn4]) = bv;
    __syncthreads();
    #pragma unroll
    for (int kk = 0; kk < 16; ++kk) {
      float4 a4 = *reinterpret_cast<const float4*>(&As[kk][ty << 2]);
      float4 b4 = *reinterpret_cast<const float4*>(&Bs[kk][tx << 2]);
      float af[4] = {a4.x, a4.y, a4.z, a4.w};
      float bf[4] = {b4.x, b4.y, b4.z, b4.w};
      #pragma unroll
      for (int i = 0; i < 4; ++i)
        #pragma unroll
        for (int j = 0; j < 4; ++j)
          acc[i][j] = fmaf(af[i], bf[j], acc[i][j]);
    }
    __syncthreads();
  }
  #pragma unroll
  for (int i = 0; i < 4; ++i) {
    float4 cv = make_float4(acc[i][0], acc[i][1], acc[i][2], acc[i][3]);
    *reinterpret_cast<float4*>(&C[(size_t)(bm + ty * 4 + i) * ldc + bn + tx * 4]) = cv;
  }
}

// ---------------- same GEMM but bf16 output ---------------------------------
__global__ __launch_bounds__(256) void gemm_f32_bf16out(
    const float* __restrict__ A, const float* __restrict__ B, unsigned short* __restrict__ C,
    int M, int N, int K, int lda, int ldb, int ldc) {
  __shared__ float As[16][68];
  __shared__ float Bs[16][68];
  const int t = threadIdx.x;
  const int bm = blockIdx.y * 64;
  const int bn = blockIdx.x * 64;
  const int tx = t & 15, ty = t >> 4;
  float acc[4][4];
  #pragma unroll
  for (int i = 0; i < 4; ++i)
    #pragma unroll
    for (int j = 0; j < 4; ++j) acc[i][j] = 0.f;

  const int am = t >> 2, akq = (t & 3) << 2;
  const int bk = t >> 4, bn4 = (t & 15) << 2;

  for (int k0 = 0; k0 < K; k0 += 16) {
    float4 av = *reinterpret_cast<const float4*>(&A[(size_t)(bm + am) * lda + k0 + akq]);
    float4 bv = *reinterpret_cast<const float4*>(&B[(size_t)(k0 + bk) * ldb + bn + bn4]);
    As[akq + 0][am] = av.x;
    As[akq + 1][am] = av.y;
    As[akq + 2][am] = av.z;
    As[akq + 3][am] = av.w;
    *reinterpret_cast<float4*>(&Bs[bk][bn4]) = bv;
    __syncthreads();
    #pragma unroll
    for (int kk = 0; kk < 16; ++kk) {
      float4 a4 = *reinterpret_cast<const float4*>(&As[kk][ty << 2]);
      float4 b4 = *reinterpret_cast<const float4*>(&Bs[kk][tx << 2]);
      float af[4] = {a4.x, a4.y, a4.z, a4.w};
      float bf[4] = {b4.x, b4.y, b4.z, b4.w};
      #pragma unroll
      for (int i = 0; i < 4; ++i)
        #pragma unroll
        for (int j = 0; j < 4; ++j)
          acc[i][j] = fmaf(af[i], bf[j], acc[i][j]);
    }
    __syncthreads();
  }
  #pragma unroll
  for (int i = 0; i < 4; ++i) {
    union { unsigned short u[4]; uint2 v; } o;
    #pragma unroll
    for (int j = 0; j < 4; ++j) o.u[j] = f2bf(acc[i][j]);
    *reinterpret_cast<uint2*>(&C[(size_t)(bm + ty * 4 + i) * ldc + bn + tx * 4]) = o.v;
  }
}

// ---------------- row-wise RMSNorm ------------------------------------------
__global__ __launch_bounds__(256) void rmsnorm_kernel(
    const float* __restrict__ in, const float* __restrict__ g, float* __restrict__ out,
    int N, int in_stride, int out_stride) {
  __shared__ float red[256];
  const int row = blockIdx.x, t = threadIdx.x;
  const float* x = in + (size_t)row * in_stride;
  float s = 0.f;
  for (int i = t; i < N; i += 256) { float v = x[i]; s += v * v; }
  red[t] = s;
  __syncthreads();
  for (int o = 128; o > 0; o >>= 1) {
    if (t < o) red[t] += red[t + o];
    __syncthreads();
  }
  const float scale = rsqrtf(red[0] / (float)N + 1e-6f);
  float* y = out + (size_t)row * out_stride;
  for (int i = t; i < N; i += 256) y[i] = x[i] * scale * g[i];
}

// ---------------- pack Q: qbf[S,5120] -> Qc[h][qsub][g8 32][row 16][8], rope fused
__global__ __launch_bounds__(256) void pack_q(
    const unsigned short* __restrict__ qbf, unsigned short* __restrict__ Qc) {
  const int qsub = blockIdx.x;   // 0..127
  const int h = blockIdx.y;
  unsigned short* dst = Qc + ((size_t)(h * 128 + qsub)) * 4096;
  const int t = threadIdx.x;
  #pragma unroll
  for (int j = 0; j < 2; ++j) {
    int s = t + 256 * j;        // 0..511
    int g8 = s >> 4, row = s & 15;
    int qrow = qsub * 16 + row;
    const unsigned short* src = qbf + (size_t)qrow * 5120 + h * 256 + g8 * 8;
    union { unsigned short u[8]; uint4 v; } o;
    if (g8 < 24) {
      o.v = *reinterpret_cast<const uint4*>(src);
    } else {
      const unsigned short* part = qbf + (size_t)qrow * 5120 + h * 256 + (g8 ^ 4) * 8;
      float pos = (float)qrow;
      #pragma unroll
      for (int e = 0; e < 8; ++e) {
        int i = g8 * 8 - 192 + e;     // 0..63
        int fi = i & 31;
        float ang = pos * exp2f(-(float)fi * 0.622861517f);  // theta^(-fi/32)
        float cs = cosf(ang), sn = sinf(ang);
        float own = bf2f(src[e]);
        float other = bf2f(part[e]);
        float val = (i < 32) ? (own * cs - other * sn) : (own * cs + other * sn);
        o.u[e] = f2bf(val);
      }
    }
    *reinterpret_cast<uint4*>(dst + s * 8) = o.v;
  }
}

// ---------------- pack K,V: kvbf + ckv(rope fp32) -> Kc, Vc -----------------
// Kc[h][kt 64][sub2][g8 32][row16][8] ; Vc[h][kt 64][vt16][g4][col16][8]
__global__ __launch_bounds__(256) void pack_kv(
    const unsigned short* __restrict__ kvbf, const float* __restrict__ ckv,
    unsigned short* __restrict__ Kc, unsigned short* __restrict__ Vc) {
  const int kt = blockIdx.x;   // 0..63
  const int h = blockIdx.y;
  const int t = threadIdx.x;
  unsigned short* kdst = Kc + ((size_t)(h * 64 + kt)) * 8192;
  unsigned short* vdst = Vc + ((size_t)(h * 64 + kt)) * 8192;
  #pragma unroll
  for (int j = 0; j < 4; ++j) {
    int s = t + 256 * j;            // 0..1023
    int sub = s >> 9, g8 = (s >> 4) & 31, row = s & 15;
    int krow = kt * 32 + sub * 16 + row;
    union { unsigned short u[8]; uint4 v; } o;
    if (g8 < 24) {
      o.v = *reinterpret_cast<const uint4*>(kvbf + (size_t)krow * 8960 + h * 448 + g8 * 8);
    } else {
      const float* kr = ckv + (size_t)krow * 576 + 512;
      float pos = (float)krow;
      #pragma unroll
      for (int e = 0; e < 8; ++e) {
        int i = g8 * 8 - 192 + e;
        int fi = i & 31;
        float ang = pos * exp2f(-(float)fi * 0.622861517f);
        float cs = cosf(ang), sn = sinf(ang);
        float own = kr[i];
        float other = kr[i < 32 ? i + 32 : i - 32];
        float val = (i < 32) ? (own * cs - other * sn) : (own * cs + other * sn);
        o.u[e] = f2bf(val);
      }
    }
    *reinterpret_cast<uint4*>(kdst + s * 8) = o.v;
  }
  #pragma unroll
  for (int j = 0; j < 4; ++j) {
    int s = t + 256 * j;
    int vt = s >> 6, gg = (s >> 4) & 3, col = s & 15;
    union { unsigned short u[8]; uint4 v; } o;
    #pragma unroll
    for (int e = 0; e < 8; ++e) {
      int krow = kt * 32 + gg * 8 + e;
      o.u[e] = kvbf[(size_t)krow * 8960 + h * 448 + 192 + vt * 16 + col];
    }
    *reinterpret_cast<uint4*>(vdst + s * 8) = o.v;
  }
}

// ---------------- MFMA flash attention --------------------------------------
// grid (32 qtiles reversed, 20 heads), 256 threads = 4 waves.
// Wave w owns q-rows [qt*64 + w*16, +16). QK and PV D-layouts share rows
// (l>>4)*4+r, so softmax state (m, l, rescale) is lane-local.
__global__ __launch_bounds__(256) void attn_mfma(
    const unsigned short* __restrict__ Qc, const unsigned short* __restrict__ Kc,
    const unsigned short* __restrict__ Vc, float* __restrict__ outp) {
  __shared__ unsigned short Ks[8192] __attribute__((aligned(16)));  // 16KB
  __shared__ unsigned short Vs[8192] __attribute__((aligned(16)));  // 16KB
  __shared__ unsigned short Ps[2048] __attribute__((aligned(16)));  // 4KB (1KB/wave)
  const int t = threadIdx.x;
  const int l = t & 63;
  const int w = t >> 6;
  const int qt = (int)gridDim.x - 1 - (int)blockIdx.x;  // big tiles first
  const int h = blockIdx.y;
  const int g = l >> 4;
  const int c = l & 15;

  // Q fragments live in registers: 8 x bf16x8 per lane
  const unsigned short* qtile = Qc + ((size_t)(h * 128 + qt * 4 + w)) * 4096;
  bf16x8 qf[8];
  #pragma unroll
  for (int st = 0; st < 8; ++st)
    qf[st] = *reinterpret_cast<const bf16x8*>(qtile + st * 512 + l * 8);

  f32x4 acc[16];
  #pragma unroll
  for (int vt = 0; vt < 16; ++vt) acc[vt] = (f32x4){0.f, 0.f, 0.f, 0.f};
  float m_r[4] = {-1e30f, -1e30f, -1e30f, -1e30f};
  float l_r[4] = {0.f, 0.f, 0.f, 0.f};

  const int niter = 2 * qt + 2;
  for (int kt = 0; kt < niter; ++kt) {
    const unsigned short* ksrc = Kc + ((size_t)(h * 64 + kt)) * 8192;
    const unsigned short* vsrc = Vc + ((size_t)(h * 64 + kt)) * 8192;
    #pragma unroll
    for (int j = 0; j < 4; ++j) {
      int s = t + 256 * j;
      *reinterpret_cast<uint4*>(&Ks[s * 8]) = *reinterpret_cast<const uint4*>(ksrc + s * 8);
      *reinterpret_cast<uint4*>(&Vs[s * 8]) = *reinterpret_cast<const uint4*>(vsrc + s * 8);
    }
    __syncthreads();

    // QK^T: S[16q x 32k], two 16-col subtiles
    f32x4 s0 = {0.f, 0.f, 0.f, 0.f}, s1 = {0.f, 0.f, 0.f, 0.f};
    #pragma unroll
    for (int st = 0; st < 8; ++st) {
      bf16x8 b0 = *reinterpret_cast<const bf16x8*>(&Ks[st * 512 + l * 8]);
      bf16x8 b1 = *reinterpret_cast<const bf16x8*>(&Ks[4096 + st * 512 + l * 8]);
      s0 = __builtin_amdgcn_mfma_f32_16x16x32_bf16(qf[st], b0, s0, 0, 0, 0);
      s1 = __builtin_amdgcn_mfma_f32_16x16x32_bf16(qf[st], b1, s1, 0, 0, 0);
    }

    // online softmax, lane-local rows (l>>4)*4+r
    const bool masked = (kt >= 2 * qt);
    float rs_r[4], p0[4], p1[4];
    #pragma unroll
    for (int r = 0; r < 4; ++r) {
      float a0 = s0[r] * 0.0625f;
      float a1 = s1[r] * 0.0625f;
      if (masked) {
        int qp = qt * 64 + w * 16 + g * 4 + r;
        if (kt * 32 + c > qp) a0 = -1e30f;
        if (kt * 32 + 16 + c > qp) a1 = -1e30f;
      }
      float mx = fmaxf(a0, a1);
      mx = fmaxf(mx, __shfl_xor(mx, 1));
      mx = fmaxf(mx, __shfl_xor(mx, 2));
      mx = fmaxf(mx, __shfl_xor(mx, 4));
      mx = fmaxf(mx, __shfl_xor(mx, 8));
      float mo = m_r[r];
      float rs, mn;
      if (mx > mo + 8.f) { mn = mx; rs = __expf(mo - mn); m_r[r] = mn; }
      else { mn = mo; rs = 1.f; }
      rs_r[r] = rs;
      float e0 = __expf(a0 - mn);
      float e1 = __expf(a1 - mn);
      p0[r] = e0; p1[r] = e1;
      float sum = e0 + e1;
      sum += __shfl_xor(sum, 1);
      sum += __shfl_xor(sum, 2);
      sum += __shfl_xor(sum, 4);
      sum += __shfl_xor(sum, 8);
      l_r[r] = l_r[r] * rs + sum;
    }

    // write P (bf16) into A-frag layout (per-wave 1KB region)
    #pragma unroll
    for (int r = 0; r < 4; ++r) {
      int qloc = g * 4 + r;
      int k0 = c;
      int k1 = 16 + c;
      Ps[w * 512 + ((k0 >> 3) << 7) + qloc * 8 + (k0 & 7)] = f2bf(p0[r]);
      Ps[w * 512 + ((k1 >> 3) << 7) + qloc * 8 + (k1 & 7)] = f2bf(p1[r]);
    }

    // deferred rescale of O accumulator
    if (rs_r[0] != 1.f || rs_r[1] != 1.f || rs_r[2] != 1.f || rs_r[3] != 1.f) {
      #pragma unroll
      for (int vt = 0; vt < 16; ++vt) {
        acc[vt][0] *= rs_r[0]; acc[vt][1] *= rs_r[1];
        acc[vt][2] *= rs_r[2]; acc[vt][3] *= rs_r[3];
      }
    }

    // PV: wave-local Ps read (in-order DS pipe; compiler inserts lgkmcnt)
    bf16x8 pa = *reinterpret_cast<const bf16x8*>(&Ps[w * 512 + l * 8]);
    #pragma unroll
    for (int vt = 0; vt < 16; ++vt) {
      bf16x8 vb = *reinterpret_cast<const bf16x8*>(&Vs[vt * 512 + l * 8]);
      acc[vt] = __builtin_amdgcn_mfma_f32_16x16x32_bf16(pa, vb, acc[vt], 0, 0, 0);
    }
    __syncthreads();
  }

  float inv[4];
  #pragma unroll
  for (int r = 0; r < 4; ++r) inv[r] = 1.f / l_r[r];
  #pragma unroll
  for (int vt = 0; vt < 16; ++vt) {
    #pragma unroll
    for (int r = 0; r < 4; ++r) {
      int row = qt * 64 + w * 16 + g * 4 + r;
      int col = h * 256 + vt * 16 + c;
      outp[(size_t)row * 5120 + col] = acc[vt][r] * inv[r];
    }
  }
}

extern "C" void kernel_launch(void* const* d_in, const int* in_sizes, int n_in,
                              void* d_out, int out_size, void* d_ws, size_t ws_size,
                              hipStream_t stream) {
  const float* hidden = (const float*)d_in[0];  // [2048, 2048]
  const float* w_q_a  = (const float*)d_in[1];  // [2048, 768]
  const float* w_q_b  = (const float*)d_in[2];  // [768, 5120]
  const float* w_kv_a = (const float*)d_in[3];  // [2048, 576]
  const float* w_kv_b = (const float*)d_in[4];  // [512, 8960]
  const float* w_o    = (const float*)d_in[5];  // [5120, 2048]
  const float* g_q_a  = (const float*)d_in[6];  // [768]
  const float* g_kv_a = (const float*)d_in[7];  // [512]
  float* out = (float*)d_out;                   // [2048, 2048]

  const int S = 2048;
  char* ws = (char*)d_ws;
  unsigned short* qbf  = (unsigned short*)(ws + 0);           // 20.97MB bf16 [S,5120]
  unsigned short* Qc   = (unsigned short*)(ws + 20971520);    // 20.97MB
  unsigned short* Kc   = (unsigned short*)(ws + 41943040);    // 20.97MB
  unsigned short* Vc   = (unsigned short*)(ws + 62914560);    // 20.97MB
  float*          q_a  = (float*)(ws + 83886080);             // 6.29MB [S,768]
  float*          ckv  = (float*)(ws + 90177536);             // 4.72MB [S,576]
  float*          kv_c = (float*)(ws + 94896128);             // 4.19MB [S,512]
  unsigned short* kvbf = (unsigned short*)(ws + 99090432);    // 36.7MB bf16 [S,8960]
  float*          attn = (float*)(ws + 83886080);             // 41.9MB overlay (q_a..kvbf dead)

  dim3 blk(256);

  gemm_f32<<<dim3(768 / 64, S / 64), blk, 0, stream>>>(hidden, w_q_a, q_a,
                                                       S, 768, 2048, 2048, 768, 768);
  rmsnorm_kernel<<<S, blk, 0, stream>>>(q_a, g_q_a, q_a, 768, 768, 768);
  gemm_f32_bf16out<<<dim3(5120 / 64, S / 64), blk, 0, stream>>>(q_a, w_q_b, qbf,
                                                                S, 5120, 768, 768, 5120, 5120);
  gemm_f32<<<dim3(576 / 64, S / 64), blk, 0, stream>>>(hidden, w_kv_a, ckv,
                                                       S, 576, 2048, 2048, 576, 576);
  rmsnorm_kernel<<<S, blk, 0, stream>>>(ckv, g_kv_a, kv_c, 512, 576, 512);
  gemm_f32_bf16out<<<dim3(8960 / 64, S / 64), blk, 0, stream>>>(kv_c, w_kv_b, kvbf,
                                                                S, 8960, 512, 512, 8960, 8960);
  pack_q<<<dim3(128, NHEADS), blk, 0, stream>>>(qbf, Qc);
  pack_kv<<<dim3(64, NHEADS), blk, 0, stream>>>(kvbf, ckv, Kc, Vc);
  attn_mfma<<<dim3(32, NHEADS), blk, 0, stream>>>(Qc, Kc, Vc, attn);
  gemm_f32<<<dim3(2048 / 64, S / 64), blk, 0, stream>>>(attn, w_o, out,
                                                        S, 2048, 5120, 5120, 2048, 2048);
}

// Round 3
// 701.313 us; speedup vs baseline: 5.4019x; 2.2295x over previous
//
#include <hip/hip_runtime.h>
#include <hip/hip_bf16.h>
#include <math.h>

#define NHEADS 20

typedef short bf16x8 __attribute__((ext_vector_type(8)));
typedef float f32x4 __attribute__((ext_vector_type(4)));

__device__ inline float bf2f(unsigned short u) {
  union { unsigned int i; float f; } x; x.i = ((unsigned int)u) << 16; return x.f;
}
__device__ inline unsigned short f2bf(float f) {
  __hip_bfloat16 h = __float2bfloat16(f);
  union { __hip_bfloat16 h; unsigned short u; } x; x.h = h; return x.u;
}
__device__ inline void gload_lds16(const void* g, void* l) {
  __builtin_amdgcn_global_load_lds(
      (const __attribute__((address_space(1))) void*)g,
      (__attribute__((address_space(3))) void*)l, 16, 0, 0);
}

// ---------------- fp32 -> bf16 copy (8 elems/thread) ------------------------
__global__ __launch_bounds__(256) void f32_to_bf16_kernel(
    const float* __restrict__ in, unsigned short* __restrict__ out, int n8) {
  int idx = blockIdx.x * 256 + threadIdx.x;
  if (idx < n8) {
    float4 a = reinterpret_cast<const float4*>(in)[idx * 2];
    float4 b = reinterpret_cast<const float4*>(in)[idx * 2 + 1];
    union { unsigned short u[8]; uint4 v; } o;
    o.u[0] = f2bf(a.x); o.u[1] = f2bf(a.y); o.u[2] = f2bf(a.z); o.u[3] = f2bf(a.w);
    o.u[4] = f2bf(b.x); o.u[5] = f2bf(b.y); o.u[6] = f2bf(b.z); o.u[7] = f2bf(b.w);
    reinterpret_cast<uint4*>(out)[idx] = o.v;
  }
}

// ---------------- fp32 [R,C] -> bf16 transposed [C,R] -----------------------
__global__ __launch_bounds__(256) void transpose_f32_bf16(
    const float* __restrict__ in, unsigned short* __restrict__ out, int R, int C0) {
  __shared__ float tile[32][33];
  const int tx = threadIdx.x, ty = threadIdx.y;
  const int bc = blockIdx.x * 32, br = blockIdx.y * 32;
  #pragma unroll
  for (int j = 0; j < 4; ++j)
    tile[ty + 8 * j][tx] = in[(size_t)(br + ty + 8 * j) * C0 + bc + tx];
  __syncthreads();
  #pragma unroll
  for (int j = 0; j < 4; ++j)
    out[(size_t)(bc + ty + 8 * j) * R + br + tx] = f2bf(tile[tx][ty + 8 * j]);
}

// ---------------- bf16 MFMA GEMM: C[M,N] = A[M,K] @ Bt[N,K]^T ---------------
// 128x128 tile, BK=32, 256 thr = 4 waves, fragment-linear LDS via
// pre-swizzled global_load_lds (16B). Wave w owns 64x64 quadrant (w>>1, w&1).
template <int BF16OUT>
__global__ __launch_bounds__(256) void gemm_mfma(
    const unsigned short* __restrict__ A, const unsigned short* __restrict__ Bt,
    void* __restrict__ Cout, int M, int N, int K) {
  __shared__ unsigned short As[4096] __attribute__((aligned(16)));  // 8 frags x 512
  __shared__ unsigned short Bs[4096] __attribute__((aligned(16)));
  const int t = threadIdx.x;
  const int l = t & 63;
  const int w = t >> 6;
  const int bm = blockIdx.y * 128;
  const int bn = blockIdx.x * 128;
  const int wr = w >> 1, wc = w & 1;
  const int lr = l & 15, lk = (l >> 4) * 8;

  f32x4 acc[4][4];
  #pragma unroll
  for (int i = 0; i < 4; ++i)
    #pragma unroll
    for (int j = 0; j < 4; ++j) acc[i][j] = (f32x4){0.f, 0.f, 0.f, 0.f};

  // per-lane global row indices for the two staged fragments
  int arow0 = bm + (w + 0) * 16 + lr;
  int arow1 = bm + (w + 4) * 16 + lr;
  int bcol0 = bn + (w + 0) * 16 + lr; if (bcol0 >= N) bcol0 = N - 1;
  int bcol1 = bn + (w + 4) * 16 + lr; if (bcol1 >= N) bcol1 = N - 1;
  const unsigned short* aptr0 = A + (size_t)arow0 * K + lk;
  const unsigned short* aptr1 = A + (size_t)arow1 * K + lk;
  const unsigned short* bptr0 = Bt + (size_t)bcol0 * K + lk;
  const unsigned short* bptr1 = Bt + (size_t)bcol1 * K + lk;

  for (int k0 = 0; k0 < K; k0 += 32) {
    gload_lds16(aptr0 + k0, &As[(w + 0) * 512]);
    gload_lds16(aptr1 + k0, &As[(w + 4) * 512]);
    gload_lds16(bptr0 + k0, &Bs[(w + 0) * 512]);
    gload_lds16(bptr1 + k0, &Bs[(w + 4) * 512]);
    __syncthreads();
    bf16x8 af[4], bfr[4];
    #pragma unroll
    for (int mi = 0; mi < 4; ++mi)
      af[mi] = *reinterpret_cast<const bf16x8*>(&As[(wr * 4 + mi) * 512 + l * 8]);
    #pragma unroll
    for (int nj = 0; nj < 4; ++nj)
      bfr[nj] = *reinterpret_cast<const bf16x8*>(&Bs[(wc * 4 + nj) * 512 + l * 8]);
    #pragma unroll
    for (int mi = 0; mi < 4; ++mi)
      #pragma unroll
      for (int nj = 0; nj < 4; ++nj)
        acc[mi][nj] = __builtin_amdgcn_mfma_f32_16x16x32_bf16(af[mi], bfr[nj], acc[mi][nj], 0, 0, 0);
    __syncthreads();
  }

  #pragma unroll
  for (int mi = 0; mi < 4; ++mi) {
    #pragma unroll
    for (int nj = 0; nj < 4; ++nj) {
      int col = bn + wc * 64 + nj * 16 + lr;
      if (col < N) {
        #pragma unroll
        for (int r = 0; r < 4; ++r) {
          int row = bm + wr * 64 + mi * 16 + (l >> 4) * 4 + r;
          if (BF16OUT)
            ((unsigned short*)Cout)[(size_t)row * N + col] = f2bf(acc[mi][nj][r]);
          else
            ((float*)Cout)[(size_t)row * N + col] = acc[mi][nj][r];
        }
      }
    }
  }
}

// ---------------- row-wise RMSNorm (fp32 in, bf16 out) ----------------------
__global__ __launch_bounds__(256) void rmsnorm_kernel(
    const float* __restrict__ in, const float* __restrict__ g, unsigned short* __restrict__ out,
    int N, int in_stride, int out_stride) {
  __shared__ float red[256];
  const int row = blockIdx.x, t = threadIdx.x;
  const float* x = in + (size_t)row * in_stride;
  float s = 0.f;
  for (int i = t; i < N; i += 256) { float v = x[i]; s += v * v; }
  red[t] = s;
  __syncthreads();
  for (int o = 128; o > 0; o >>= 1) {
    if (t < o) red[t] += red[t + o];
    __syncthreads();
  }
  const float scale = rsqrtf(red[0] / (float)N + 1e-6f);
  unsigned short* y = out + (size_t)row * out_stride;
  for (int i = t; i < N; i += 256) y[i] = f2bf(x[i] * scale * g[i]);
}

// ---------------- pack Q: qbf[S,5120] -> Qc[h][qsub][frag], rope fused ------
__global__ __launch_bounds__(256) void pack_q(
    const unsigned short* __restrict__ qbf, unsigned short* __restrict__ Qc) {
  const int qsub = blockIdx.x;   // 0..127
  const int h = blockIdx.y;
  unsigned short* dst = Qc + ((size_t)(h * 128 + qsub)) * 4096;
  const int t = threadIdx.x;
  #pragma unroll
  for (int j = 0; j < 2; ++j) {
    int s = t + 256 * j;        // 0..511
    int g8 = s >> 4, row = s & 15;
    int qrow = qsub * 16 + row;
    const unsigned short* src = qbf + (size_t)qrow * 5120 + h * 256 + g8 * 8;
    union { unsigned short u[8]; uint4 v; } o;
    if (g8 < 24) {
      o.v = *reinterpret_cast<const uint4*>(src);
    } else {
      const unsigned short* part = qbf + (size_t)qrow * 5120 + h * 256 + (g8 ^ 4) * 8;
      float pos = (float)qrow;
      #pragma unroll
      for (int e = 0; e < 8; ++e) {
        int i = g8 * 8 - 192 + e;     // 0..63
        int fi = i & 31;
        float ang = pos * exp2f(-(float)fi * 0.622861517f);
        float cs = cosf(ang), sn = sinf(ang);
        float own = bf2f(src[e]);
        float other = bf2f(part[e]);
        float val = (i < 32) ? (own * cs - other * sn) : (own * cs + other * sn);
        o.u[e] = f2bf(val);
      }
    }
    *reinterpret_cast<uint4*>(dst + s * 8) = o.v;
  }
}

// ---------------- pack K,V ---------------------------------------------------
__global__ __launch_bounds__(256) void pack_kv(
    const unsigned short* __restrict__ kvbf, const float* __restrict__ ckv,
    unsigned short* __restrict__ Kc, unsigned short* __restrict__ Vc) {
  const int kt = blockIdx.x;   // 0..63
  const int h = blockIdx.y;
  const int t = threadIdx.x;
  unsigned short* kdst = Kc + ((size_t)(h * 64 + kt)) * 8192;
  unsigned short* vdst = Vc + ((size_t)(h * 64 + kt)) * 8192;
  #pragma unroll
  for (int j = 0; j < 4; ++j) {
    int s = t + 256 * j;            // 0..1023
    int sub = s >> 9, g8 = (s >> 4) & 31, row = s & 15;
    int krow = kt * 32 + sub * 16 + row;
    union { unsigned short u[8]; uint4 v; } o;
    if (g8 < 24) {
      o.v = *reinterpret_cast<const uint4*>(kvbf + (size_t)krow * 8960 + h * 448 + g8 * 8);
    } else {
      const float* kr = ckv + (size_t)krow * 576 + 512;
      float pos = (float)krow;
      #pragma unroll
      for (int e = 0; e < 8; ++e) {
        int i = g8 * 8 - 192 + e;
        int fi = i & 31;
        float ang = pos * exp2f(-(float)fi * 0.622861517f);
        float cs = cosf(ang), sn = sinf(ang);
        float own = kr[i];
        float other = kr[i < 32 ? i + 32 : i - 32];
        float val = (i < 32) ? (own * cs - other * sn) : (own * cs + other * sn);
        o.u[e] = f2bf(val);
      }
    }
    *reinterpret_cast<uint4*>(kdst + s * 8) = o.v;
  }
  #pragma unroll
  for (int j = 0; j < 4; ++j) {
    int s = t + 256 * j;
    int vt = s >> 6, gg = (s >> 4) & 3, col = s & 15;
    union { unsigned short u[8]; uint4 v; } o;
    #pragma unroll
    for (int e = 0; e < 8; ++e) {
      int krow = kt * 32 + gg * 8 + e;
      o.u[e] = kvbf[(size_t)krow * 8960 + h * 448 + 192 + vt * 16 + col];
    }
    *reinterpret_cast<uint4*>(vdst + s * 8) = o.v;
  }
}

// ---------------- MFMA flash attention (bf16 out) ---------------------------
__global__ __launch_bounds__(256) void attn_mfma(
    const unsigned short* __restrict__ Qc, const unsigned short* __restrict__ Kc,
    const unsigned short* __restrict__ Vc, unsigned short* __restrict__ outp) {
  __shared__ unsigned short Ks[8192] __attribute__((aligned(16)));
  __shared__ unsigned short Vs[8192] __attribute__((aligned(16)));
  __shared__ unsigned short Ps[2048] __attribute__((aligned(16)));
  const int t = threadIdx.x;
  const int l = t & 63;
  const int w = t >> 6;
  const int qt = (int)gridDim.x - 1 - (int)blockIdx.x;
  const int h = blockIdx.y;
  const int g = l >> 4;
  const int c = l & 15;

  const unsigned short* qtile = Qc + ((size_t)(h * 128 + qt * 4 + w)) * 4096;
  bf16x8 qf[8];
  #pragma unroll
  for (int st = 0; st < 8; ++st)
    qf[st] = *reinterpret_cast<const bf16x8*>(qtile + st * 512 + l * 8);

  f32x4 acc[16];
  #pragma unroll
  for (int vt = 0; vt < 16; ++vt) acc[vt] = (f32x4){0.f, 0.f, 0.f, 0.f};
  float m_r[4] = {-1e30f, -1e30f, -1e30f, -1e30f};
  float l_r[4] = {0.f, 0.f, 0.f, 0.f};

  const int niter = 2 * qt + 2;
  for (int kt = 0; kt < niter; ++kt) {
    const unsigned short* ksrc = Kc + ((size_t)(h * 64 + kt)) * 8192;
    const unsigned short* vsrc = Vc + ((size_t)(h * 64 + kt)) * 8192;
    #pragma unroll
    for (int j = 0; j < 4; ++j) {
      int s = t + 256 * j;
      *reinterpret_cast<uint4*>(&Ks[s * 8]) = *reinterpret_cast<const uint4*>(ksrc + s * 8);
      *reinterpret_cast<uint4*>(&Vs[s * 8]) = *reinterpret_cast<const uint4*>(vsrc + s * 8);
    }
    __syncthreads();

    f32x4 s0 = {0.f, 0.f, 0.f, 0.f}, s1 = {0.f, 0.f, 0.f, 0.f};
    #pragma unroll
    for (int st = 0; st < 8; ++st) {
      bf16x8 b0 = *reinterpret_cast<const bf16x8*>(&Ks[st * 512 + l * 8]);
      bf16x8 b1 = *reinterpret_cast<const bf16x8*>(&Ks[4096 + st * 512 + l * 8]);
      s0 = __builtin_amdgcn_mfma_f32_16x16x32_bf16(qf[st], b0, s0, 0, 0, 0);
      s1 = __builtin_amdgcn_mfma_f32_16x16x32_bf16(qf[st], b1, s1, 0, 0, 0);
    }

    const bool masked = (kt >= 2 * qt);
    float rs_r[4], p0[4], p1[4];
    #pragma unroll
    for (int r = 0; r < 4; ++r) {
      float a0 = s0[r] * 0.0625f;
      float a1 = s1[r] * 0.0625f;
      if (masked) {
        int qp = qt * 64 + w * 16 + g * 4 + r;
        if (kt * 32 + c > qp) a0 = -1e30f;
        if (kt * 32 + 16 + c > qp) a1 = -1e30f;
      }
      float mx = fmaxf(a0, a1);
      mx = fmaxf(mx, __shfl_xor(mx, 1));
      mx = fmaxf(mx, __shfl_xor(mx, 2));
      mx = fmaxf(mx, __shfl_xor(mx, 4));
      mx = fmaxf(mx, __shfl_xor(mx, 8));
      float mo = m_r[r];
      float rs, mn;
      if (mx > mo + 8.f) { mn = mx; rs = __expf(mo - mn); m_r[r] = mn; }
      else { mn = mo; rs = 1.f; }
      rs_r[r] = rs;
      float e0 = __expf(a0 - mn);
      float e1 = __expf(a1 - mn);
      p0[r] = e0; p1[r] = e1;
      float sum = e0 + e1;
      sum += __shfl_xor(sum, 1);
      sum += __shfl_xor(sum, 2);
      sum += __shfl_xor(sum, 4);
      sum += __shfl_xor(sum, 8);
      l_r[r] = l_r[r] * rs + sum;
    }

    #pragma unroll
    for (int r = 0; r < 4; ++r) {
      int qloc = g * 4 + r;
      int k0 = c;
      int k1 = 16 + c;
      Ps[w * 512 + ((k0 >> 3) << 7) + qloc * 8 + (k0 & 7)] = f2bf(p0[r]);
      Ps[w * 512 + ((k1 >> 3) << 7) + qloc * 8 + (k1 & 7)] = f2bf(p1[r]);
    }

    if (rs_r[0] != 1.f || rs_r[1] != 1.f || rs_r[2] != 1.f || rs_r[3] != 1.f) {
      #pragma unroll
      for (int vt = 0; vt < 16; ++vt) {
        acc[vt][0] *= rs_r[0]; acc[vt][1] *= rs_r[1];
        acc[vt][2] *= rs_r[2]; acc[vt][3] *= rs_r[3];
      }
    }

    bf16x8 pa = *reinterpret_cast<const bf16x8*>(&Ps[w * 512 + l * 8]);
    #pragma unroll
    for (int vt = 0; vt < 16; ++vt) {
      bf16x8 vb = *reinterpret_cast<const bf16x8*>(&Vs[vt * 512 + l * 8]);
      acc[vt] = __builtin_amdgcn_mfma_f32_16x16x32_bf16(pa, vb, acc[vt], 0, 0, 0);
    }
    __syncthreads();
  }

  float inv[4];
  #pragma unroll
  for (int r = 0; r < 4; ++r) inv[r] = 1.f / l_r[r];
  #pragma unroll
  for (int vt = 0; vt < 16; ++vt) {
    #pragma unroll
    for (int r = 0; r < 4; ++r) {
      int row = qt * 64 + w * 16 + g * 4 + r;
      int col = h * 256 + vt * 16 + c;
      outp[(size_t)row * 5120 + col] = f2bf(acc[vt][r] * inv[r]);
    }
  }
}

extern "C" void kernel_launch(void* const* d_in, const int* in_sizes, int n_in,
                              void* d_out, int out_size, void* d_ws, size_t ws_size,
                              hipStream_t stream) {
  const float* hidden = (const float*)d_in[0];  // [2048, 2048]
  const float* w_q_a  = (const float*)d_in[1];  // [2048, 768]
  const float* w_q_b  = (const float*)d_in[2];  // [768, 5120]
  const float* w_kv_a = (const float*)d_in[3];  // [2048, 576]
  const float* w_kv_b = (const float*)d_in[4];  // [512, 8960]
  const float* w_o    = (const float*)d_in[5];  // [5120, 2048]
  const float* g_q_a  = (const float*)d_in[6];  // [768]
  const float* g_kv_a = (const float*)d_in[7];  // [512]
  float* out = (float*)d_out;                   // [2048, 2048]

  const int S = 2048;
  char* ws = (char*)d_ws;
  // overlay plan (bytes); peak 146.3 MB (< 158 MB proven in round 1)
  unsigned short* wo_t    = (unsigned short*)(ws + 0);          // [2048,5120] bf16, live all
  unsigned short* Qc      = (unsigned short*)(ws + 20971520);   // 21.0MB (after step 9)
  unsigned short* wqa_t   = (unsigned short*)(ws + 20971520);   //   [768,2048]
  unsigned short* wqb_t   = (unsigned short*)(ws + 24117248);   //   [5120,768]
  float*          q_a     = (float*)(ws + 31981568);            //   [2048,768] f32
  unsigned short* Kc      = (unsigned short*)(ws + 41943040);   // 21.0MB (after step 10)
  unsigned short* wkva_t  = (unsigned short*)(ws + 41943040);   //   [576,2048]
  unsigned short* wkvb_t  = (unsigned short*)(ws + 44302336);   //   [8960,512]
  unsigned short* kv_c    = (unsigned short*)(ws + 53477376);   //   [2048,512] bf16
  unsigned short* q_c     = (unsigned short*)(ws + 55574528);   //   [2048,768] bf16
  unsigned short* Vc      = (unsigned short*)(ws + 62914560);   // 21.0MB (after step 10)
  unsigned short* hid_bf  = (unsigned short*)(ws + 62914560);   //   [2048,2048] bf16
  float*          ckv     = (float*)(ws + 83886080);            // [2048,576] f32
  unsigned short* qbf     = (unsigned short*)(ws + 88604672);   // [2048,5120] bf16
  unsigned short* attn_bf = (unsigned short*)(ws + 88604672);   //   overlay after pack_q
  unsigned short* kvbf    = (unsigned short*)(ws + 109576192);  // [2048,8960] bf16

  dim3 blk(256);
  dim3 tblk(32, 8);

  // 1. conversions / transposes
  f32_to_bf16_kernel<<<2048, blk, 0, stream>>>(hidden, hid_bf, S * 2048 / 8);
  transpose_f32_bf16<<<dim3(768 / 32, 2048 / 32), tblk, 0, stream>>>(w_q_a, wqa_t, 2048, 768);
  transpose_f32_bf16<<<dim3(5120 / 32, 768 / 32), tblk, 0, stream>>>(w_q_b, wqb_t, 768, 5120);
  transpose_f32_bf16<<<dim3(576 / 32, 2048 / 32), tblk, 0, stream>>>(w_kv_a, wkva_t, 2048, 576);
  transpose_f32_bf16<<<dim3(8960 / 32, 512 / 32), tblk, 0, stream>>>(w_kv_b, wkvb_t, 512, 8960);
  transpose_f32_bf16<<<dim3(2048 / 32, 5120 / 32), tblk, 0, stream>>>(w_o, wo_t, 5120, 2048);

  // 2. projections
  gemm_mfma<0><<<dim3(6, 16), blk, 0, stream>>>(hid_bf, wqa_t, q_a, S, 768, 2048);
  rmsnorm_kernel<<<S, blk, 0, stream>>>(q_a, g_q_a, q_c, 768, 768, 768);
  gemm_mfma<1><<<dim3(40, 16), blk, 0, stream>>>(q_c, wqb_t, qbf, S, 5120, 768);
  gemm_mfma<0><<<dim3(5, 16), blk, 0, stream>>>(hid_bf, wkva_t, ckv, S, 576, 2048);
  rmsnorm_kernel<<<S, blk, 0, stream>>>(ckv, g_kv_a, kv_c, 512, 576, 512);
  gemm_mfma<1><<<dim3(70, 16), blk, 0, stream>>>(kv_c, wkvb_t, kvbf, S, 8960, 512);

  // 3. attention
  pack_q<<<dim3(128, NHEADS), blk, 0, stream>>>(qbf, Qc);
  pack_kv<<<dim3(64, NHEADS), blk, 0, stream>>>(kvbf, ckv, Kc, Vc);
  attn_mfma<<<dim3(32, NHEADS), blk, 0, stream>>>(Qc, Kc, Vc, attn_bf);

  // 4. output projection
  gemm_mfma<0><<<dim3(16, 16), blk, 0, stream>>>(attn_bf, wo_t, out, S, 2048, 5120);
}

// Round 4
// 585.677 us; speedup vs baseline: 6.4684x; 1.1974x over previous
//
#include <hip/hip_runtime.h>
#include <hip/hip_bf16.h>
#include <math.h>

#define NHEADS 20

typedef short bf16x8 __attribute__((ext_vector_type(8)));
typedef float f32x4 __attribute__((ext_vector_type(4)));

__device__ inline float bf2f(unsigned short u) {
  union { unsigned int i; float f; } x; x.i = ((unsigned int)u) << 16; return x.f;
}
__device__ inline unsigned short f2bf(float f) {
  __hip_bfloat16 h = __float2bfloat16(f);
  union { __hip_bfloat16 h; unsigned short u; } x; x.h = h; return x.u;
}
__device__ inline void gload_lds16(const void* g, void* l) {
  __builtin_amdgcn_global_load_lds(
      (const __attribute__((address_space(1))) void*)g,
      (__attribute__((address_space(3))) void*)l, 16, 0, 0);
}

// ---------------- fp32 -> bf16 copy (8 elems/thread) ------------------------
__global__ __launch_bounds__(256) void f32_to_bf16_kernel(
    const float* __restrict__ in, unsigned short* __restrict__ out, int n8) {
  int idx = blockIdx.x * 256 + threadIdx.x;
  if (idx < n8) {
    float4 a = reinterpret_cast<const float4*>(in)[idx * 2];
    float4 b = reinterpret_cast<const float4*>(in)[idx * 2 + 1];
    union { unsigned short u[8]; uint4 v; } o;
    o.u[0] = f2bf(a.x); o.u[1] = f2bf(a.y); o.u[2] = f2bf(a.z); o.u[3] = f2bf(a.w);
    o.u[4] = f2bf(b.x); o.u[5] = f2bf(b.y); o.u[6] = f2bf(b.z); o.u[7] = f2bf(b.w);
    reinterpret_cast<uint4*>(out)[idx] = o.v;
  }
}

// ---------------- fp32 [R,C] -> bf16 transposed [C,R] -----------------------
__global__ __launch_bounds__(256) void transpose_f32_bf16(
    const float* __restrict__ in, unsigned short* __restrict__ out, int R, int C0) {
  __shared__ float tile[32][33];
  const int tx = threadIdx.x, ty = threadIdx.y;
  const int bc = blockIdx.x * 32, br = blockIdx.y * 32;
  #pragma unroll
  for (int j = 0; j < 4; ++j)
    tile[ty + 8 * j][tx] = in[(size_t)(br + ty + 8 * j) * C0 + bc + tx];
  __syncthreads();
  #pragma unroll
  for (int j = 0; j < 4; ++j)
    out[(size_t)(bc + ty + 8 * j) * R + br + tx] = f2bf(tile[tx][ty + 8 * j]);
}

// ---------------- elementwise multi-part reduce (float4) --------------------
__global__ __launch_bounds__(256) void reduce_add_kernel(
    const float* __restrict__ in, float* __restrict__ out, int n4, int parts, size_t stride4) {
  int idx = blockIdx.x * 256 + threadIdx.x;
  if (idx < n4) {
    const float4* in4 = reinterpret_cast<const float4*>(in);
    float4 s = in4[idx];
    for (int p = 1; p < parts; ++p) {
      float4 b = in4[idx + p * stride4];
      s.x += b.x; s.y += b.y; s.z += b.z; s.w += b.w;
    }
    reinterpret_cast<float4*>(out)[idx] = s;
  }
}

// ---------------- bf16 MFMA GEMM, 2-phase dbuf, optional split-K ------------
// C[M,N] = A[M,K] @ Bt[N,K]^T over K range [z*ksize, (z+1)*ksize).
// If gridDim.z>1: write f32 partial at Cout + z*M*N.
template <int BF16OUT>
__global__ __launch_bounds__(256) void gemm_mfma(
    const unsigned short* __restrict__ A, const unsigned short* __restrict__ Bt,
    void* __restrict__ Cout, int M, int N, int K, int ksize) {
  __shared__ unsigned short As[2][4096] __attribute__((aligned(16)));
  __shared__ unsigned short Bs[2][4096] __attribute__((aligned(16)));
  const int t = threadIdx.x;
  const int l = t & 63;
  const int w = t >> 6;
  const int bm = blockIdx.y * 128;
  const int bn = blockIdx.x * 128;
  const int kbase = blockIdx.z * ksize;
  const int wr = w >> 1, wc = w & 1;
  const int lr = l & 15, lk = (l >> 4) * 8;

  f32x4 acc[4][4];
  #pragma unroll
  for (int i = 0; i < 4; ++i)
    #pragma unroll
    for (int j = 0; j < 4; ++j) acc[i][j] = (f32x4){0.f, 0.f, 0.f, 0.f};

  int arow0 = bm + (w + 0) * 16 + lr;
  int arow1 = bm + (w + 4) * 16 + lr;
  int bcol0 = bn + (w + 0) * 16 + lr; if (bcol0 >= N) bcol0 = N - 1;
  int bcol1 = bn + (w + 4) * 16 + lr; if (bcol1 >= N) bcol1 = N - 1;
  const unsigned short* aptr0 = A + (size_t)arow0 * K + kbase + lk;
  const unsigned short* aptr1 = A + (size_t)arow1 * K + kbase + lk;
  const unsigned short* bptr0 = Bt + (size_t)bcol0 * K + kbase + lk;
  const unsigned short* bptr1 = Bt + (size_t)bcol1 * K + kbase + lk;

#define GEMM_STAGE(buf, koff)                                  \
  gload_lds16(aptr0 + (koff), &As[buf][(w + 0) * 512]);        \
  gload_lds16(aptr1 + (koff), &As[buf][(w + 4) * 512]);        \
  gload_lds16(bptr0 + (koff), &Bs[buf][(w + 0) * 512]);        \
  gload_lds16(bptr1 + (koff), &Bs[buf][(w + 4) * 512]);

  GEMM_STAGE(0, 0)
  int cur = 0;
  for (int k0 = 0; k0 < ksize; k0 += 32) {
    if (k0 + 32 < ksize) {
      GEMM_STAGE(cur ^ 1, k0 + 32)
      asm volatile("s_waitcnt vmcnt(4)" ::: "memory");
    } else {
      asm volatile("s_waitcnt vmcnt(0)" ::: "memory");
    }
    __builtin_amdgcn_s_barrier();
    bf16x8 af[4], bfr[4];
    #pragma unroll
    for (int mi = 0; mi < 4; ++mi)
      af[mi] = *reinterpret_cast<const bf16x8*>(&As[cur][(wr * 4 + mi) * 512 + l * 8]);
    #pragma unroll
    for (int nj = 0; nj < 4; ++nj)
      bfr[nj] = *reinterpret_cast<const bf16x8*>(&Bs[cur][(wc * 4 + nj) * 512 + l * 8]);
    #pragma unroll
    for (int mi = 0; mi < 4; ++mi)
      #pragma unroll
      for (int nj = 0; nj < 4; ++nj)
        acc[mi][nj] = __builtin_amdgcn_mfma_f32_16x16x32_bf16(af[mi], bfr[nj], acc[mi][nj], 0, 0, 0);
    __builtin_amdgcn_s_barrier();
    cur ^= 1;
  }
#undef GEMM_STAGE

  const bool split = (gridDim.z > 1);
  float* cf = (float*)Cout + (split ? (size_t)blockIdx.z * M * N : 0);
  #pragma unroll
  for (int mi = 0; mi < 4; ++mi) {
    #pragma unroll
    for (int nj = 0; nj < 4; ++nj) {
      int col = bn + wc * 64 + nj * 16 + lr;
      if (col < N) {
        #pragma unroll
        for (int r = 0; r < 4; ++r) {
          int row = bm + wr * 64 + mi * 16 + (l >> 4) * 4 + r;
          if (!split && BF16OUT)
            ((unsigned short*)Cout)[(size_t)row * N + col] = f2bf(acc[mi][nj][r]);
          else
            cf[(size_t)row * N + col] = acc[mi][nj][r];
        }
      }
    }
  }
}

// ---------------- RMSNorm (fp32 in, bf16 out) -------------------------------
__global__ __launch_bounds__(256) void rmsnorm_kernel(
    const float* __restrict__ in, const float* __restrict__ g, unsigned short* __restrict__ out,
    int N, int in_stride, int out_stride) {
  __shared__ float red[256];
  const int row = blockIdx.x, t = threadIdx.x;
  const float* x = in + (size_t)row * in_stride;
  float s = 0.f;
  for (int i = t; i < N; i += 256) { float v = x[i]; s += v * v; }
  red[t] = s;
  __syncthreads();
  for (int o = 128; o > 0; o >>= 1) {
    if (t < o) red[t] += red[t + o];
    __syncthreads();
  }
  const float scale = rsqrtf(red[0] / (float)N + 1e-6f);
  unsigned short* y = out + (size_t)row * out_stride;
  for (int i = t; i < N; i += 256) y[i] = f2bf(x[i] * scale * g[i]);
}

// ---------------- fused 4-part reduce + RMSNorm (N=768) ---------------------
__global__ __launch_bounds__(256) void rmsnorm4_kernel(
    const float* __restrict__ parts, const float* __restrict__ g,
    unsigned short* __restrict__ out, size_t pstride) {
  __shared__ float red[256];
  const int row = blockIdx.x, t = threadIdx.x;
  const float* x = parts + (size_t)row * 768;
  float v[3];
  float s = 0.f;
  #pragma unroll
  for (int e = 0; e < 3; ++e) {
    int i = t + 256 * e;
    float a = x[i] + x[i + pstride] + x[i + 2 * pstride] + x[i + 3 * pstride];
    v[e] = a;
    s += a * a;
  }
  red[t] = s;
  __syncthreads();
  for (int o = 128; o > 0; o >>= 1) {
    if (t < o) red[t] += red[t + o];
    __syncthreads();
  }
  const float scale = rsqrtf(red[0] / 768.f + 1e-6f);
  unsigned short* y = out + (size_t)row * 768;
  #pragma unroll
  for (int e = 0; e < 3; ++e) {
    int i = t + 256 * e;
    y[i] = f2bf(v[e] * scale * g[i]);
  }
}

// ---------------- pack Q (rope fused) ---------------------------------------
__global__ __launch_bounds__(256) void pack_q(
    const unsigned short* __restrict__ qbf, unsigned short* __restrict__ Qc) {
  const int qsub = blockIdx.x;   // 0..127
  const int h = blockIdx.y;
  unsigned short* dst = Qc + ((size_t)(h * 128 + qsub)) * 4096;
  const int t = threadIdx.x;
  #pragma unroll
  for (int j = 0; j < 2; ++j) {
    int s = t + 256 * j;
    int g8 = s >> 4, row = s & 15;
    int qrow = qsub * 16 + row;
    const unsigned short* src = qbf + (size_t)qrow * 5120 + h * 256 + g8 * 8;
    union { unsigned short u[8]; uint4 v; } o;
    if (g8 < 24) {
      o.v = *reinterpret_cast<const uint4*>(src);
    } else {
      const unsigned short* part = qbf + (size_t)qrow * 5120 + h * 256 + (g8 ^ 4) * 8;
      float pos = (float)qrow;
      #pragma unroll
      for (int e = 0; e < 8; ++e) {
        int i = g8 * 8 - 192 + e;
        int fi = i & 31;
        float ang = pos * exp2f(-(float)fi * 0.622861517f);
        float cs = cosf(ang), sn = sinf(ang);
        float own = bf2f(src[e]);
        float other = bf2f(part[e]);
        float val = (i < 32) ? (own * cs - other * sn) : (own * cs + other * sn);
        o.u[e] = f2bf(val);
      }
    }
    *reinterpret_cast<uint4*>(dst + s * 8) = o.v;
  }
}

// ---------------- pack K,V ---------------------------------------------------
__global__ __launch_bounds__(256) void pack_kv(
    const unsigned short* __restrict__ kvbf, const float* __restrict__ ckv,
    unsigned short* __restrict__ Kc, unsigned short* __restrict__ Vc) {
  const int kt = blockIdx.x;   // 0..63
  const int h = blockIdx.y;
  const int t = threadIdx.x;
  unsigned short* kdst = Kc + ((size_t)(h * 64 + kt)) * 8192;
  unsigned short* vdst = Vc + ((size_t)(h * 64 + kt)) * 8192;
  #pragma unroll
  for (int j = 0; j < 4; ++j) {
    int s = t + 256 * j;
    int sub = s >> 9, g8 = (s >> 4) & 31, row = s & 15;
    int krow = kt * 32 + sub * 16 + row;
    union { unsigned short u[8]; uint4 v; } o;
    if (g8 < 24) {
      o.v = *reinterpret_cast<const uint4*>(kvbf + (size_t)krow * 8960 + h * 448 + g8 * 8);
    } else {
      const float* kr = ckv + (size_t)krow * 576 + 512;
      float pos = (float)krow;
      #pragma unroll
      for (int e = 0; e < 8; ++e) {
        int i = g8 * 8 - 192 + e;
        int fi = i & 31;
        float ang = pos * exp2f(-(float)fi * 0.622861517f);
        float cs = cosf(ang), sn = sinf(ang);
        float own = kr[i];
        float other = kr[i < 32 ? i + 32 : i - 32];
        float val = (i < 32) ? (own * cs - other * sn) : (own * cs + other * sn);
        o.u[e] = f2bf(val);
      }
    }
    *reinterpret_cast<uint4*>(kdst + s * 8) = o.v;
  }
  #pragma unroll
  for (int j = 0; j < 4; ++j) {
    int s = t + 256 * j;
    int vt = s >> 6, gg = (s >> 4) & 3, col = s & 15;
    union { unsigned short u[8]; uint4 v; } o;
    #pragma unroll
    for (int e = 0; e < 8; ++e) {
      int krow = kt * 32 + gg * 8 + e;
      o.u[e] = kvbf[(size_t)krow * 8960 + h * 448 + 192 + vt * 16 + col];
    }
    *reinterpret_cast<uint4*>(vdst + s * 8) = o.v;
  }
}

// ---------------- MFMA flash attention, 2-phase dbuf ------------------------
__global__ __launch_bounds__(256) void attn_mfma(
    const unsigned short* __restrict__ Qc, const unsigned short* __restrict__ Kc,
    const unsigned short* __restrict__ Vc, unsigned short* __restrict__ outp) {
  __shared__ unsigned short Ks[2][8192] __attribute__((aligned(16)));
  __shared__ unsigned short Vs[2][8192] __attribute__((aligned(16)));
  __shared__ unsigned short Ps[2048] __attribute__((aligned(16)));
  const int t = threadIdx.x;
  const int l = t & 63;
  const int w = t >> 6;
  const int qt = (int)gridDim.x - 1 - (int)blockIdx.x;
  const int h = blockIdx.y;
  const int g = l >> 4;
  const int c = l & 15;

  const unsigned short* qtile = Qc + ((size_t)(h * 128 + qt * 4 + w)) * 4096;
  bf16x8 qf[8];
  #pragma unroll
  for (int st = 0; st < 8; ++st)
    qf[st] = *reinterpret_cast<const bf16x8*>(qtile + st * 512 + l * 8);

  f32x4 acc[16];
  #pragma unroll
  for (int vt = 0; vt < 16; ++vt) acc[vt] = (f32x4){0.f, 0.f, 0.f, 0.f};
  float m_r[4] = {-1e30f, -1e30f, -1e30f, -1e30f};
  float l_r[4] = {0.f, 0.f, 0.f, 0.f};

  const unsigned short* kbase_p = Kc + (size_t)h * 64 * 8192 + (w * 4) * 512 + l * 8;
  const unsigned short* vbase_p = Vc + (size_t)h * 64 * 8192 + (w * 4) * 512 + l * 8;

#define ATTN_STAGE(buf, tile)                                                  \
  {                                                                            \
    const unsigned short* ks_ = kbase_p + (size_t)(tile) * 8192;               \
    const unsigned short* vs_ = vbase_p + (size_t)(tile) * 8192;               \
    gload_lds16(ks_ + 0 * 512, &Ks[buf][(w * 4 + 0) * 512]);                   \
    gload_lds16(ks_ + 1 * 512, &Ks[buf][(w * 4 + 1) * 512]);                   \
    gload_lds16(ks_ + 2 * 512, &Ks[buf][(w * 4 + 2) * 512]);                   \
    gload_lds16(ks_ + 3 * 512, &Ks[buf][(w * 4 + 3) * 512]);                   \
    gload_lds16(vs_ + 0 * 512, &Vs[buf][(w * 4 + 0) * 512]);                   \
    gload_lds16(vs_ + 1 * 512, &Vs[buf][(w * 4 + 1) * 512]);                   \
    gload_lds16(vs_ + 2 * 512, &Vs[buf][(w * 4 + 2) * 512]);                   \
    gload_lds16(vs_ + 3 * 512, &Vs[buf][(w * 4 + 3) * 512]);                   \
  }

  const int niter = 2 * qt + 2;
  ATTN_STAGE(0, 0)
  int cur = 0;
  for (int kt = 0; kt < niter; ++kt) {
    if (kt + 1 < niter) {
      ATTN_STAGE(cur ^ 1, kt + 1)
      asm volatile("s_waitcnt vmcnt(8)" ::: "memory");
    } else {
      asm volatile("s_waitcnt vmcnt(0)" ::: "memory");
    }
    __builtin_amdgcn_s_barrier();

    f32x4 s0 = {0.f, 0.f, 0.f, 0.f}, s1 = {0.f, 0.f, 0.f, 0.f};
    #pragma unroll
    for (int st = 0; st < 8; ++st) {
      bf16x8 b0 = *reinterpret_cast<const bf16x8*>(&Ks[cur][st * 512 + l * 8]);
      bf16x8 b1 = *reinterpret_cast<const bf16x8*>(&Ks[cur][4096 + st * 512 + l * 8]);
      s0 = __builtin_amdgcn_mfma_f32_16x16x32_bf16(qf[st], b0, s0, 0, 0, 0);
      s1 = __builtin_amdgcn_mfma_f32_16x16x32_bf16(qf[st], b1, s1, 0, 0, 0);
    }

    const bool masked = (kt >= 2 * qt);
    float rs_r[4], p0[4], p1[4];
    #pragma unroll
    for (int r = 0; r < 4; ++r) {
      float a0 = s0[r] * 0.0625f;
      float a1 = s1[r] * 0.0625f;
      if (masked) {
        int qp = qt * 64 + w * 16 + g * 4 + r;
        if (kt * 32 + c > qp) a0 = -1e30f;
        if (kt * 32 + 16 + c > qp) a1 = -1e30f;
      }
      float mx = fmaxf(a0, a1);
      mx = fmaxf(mx, __shfl_xor(mx, 1));
      mx = fmaxf(mx, __shfl_xor(mx, 2));
      mx = fmaxf(mx, __shfl_xor(mx, 4));
      mx = fmaxf(mx, __shfl_xor(mx, 8));
      float mo = m_r[r];
      float rs, mn;
      if (mx > mo + 8.f) { mn = mx; rs = __expf(mo - mn); m_r[r] = mn; }
      else { mn = mo; rs = 1.f; }
      rs_r[r] = rs;
      float e0 = __expf(a0 - mn);
      float e1 = __expf(a1 - mn);
      p0[r] = e0; p1[r] = e1;
      float sum = e0 + e1;
      sum += __shfl_xor(sum, 1);
      sum += __shfl_xor(sum, 2);
      sum += __shfl_xor(sum, 4);
      sum += __shfl_xor(sum, 8);
      l_r[r] = l_r[r] * rs + sum;
    }

    #pragma unroll
    for (int r = 0; r < 4; ++r) {
      int qloc = g * 4 + r;
      int k0 = c;
      int k1 = 16 + c;
      Ps[w * 512 + ((k0 >> 3) << 7) + qloc * 8 + (k0 & 7)] = f2bf(p0[r]);
      Ps[w * 512 + ((k1 >> 3) << 7) + qloc * 8 + (k1 & 7)] = f2bf(p1[r]);
    }

    if (rs_r[0] != 1.f || rs_r[1] != 1.f || rs_r[2] != 1.f || rs_r[3] != 1.f) {
      #pragma unroll
      for (int vt = 0; vt < 16; ++vt) {
        acc[vt][0] *= rs_r[0]; acc[vt][1] *= rs_r[1];
        acc[vt][2] *= rs_r[2]; acc[vt][3] *= rs_r[3];
      }
    }

    bf16x8 pa = *reinterpret_cast<const bf16x8*>(&Ps[w * 512 + l * 8]);
    #pragma unroll
    for (int vt = 0; vt < 16; ++vt) {
      bf16x8 vb = *reinterpret_cast<const bf16x8*>(&Vs[cur][vt * 512 + l * 8]);
      acc[vt] = __builtin_amdgcn_mfma_f32_16x16x32_bf16(pa, vb, acc[vt], 0, 0, 0);
    }
    __builtin_amdgcn_s_barrier();
    cur ^= 1;
  }
#undef ATTN_STAGE

  float inv[4];
  #pragma unroll
  for (int r = 0; r < 4; ++r) inv[r] = 1.f / l_r[r];
  #pragma unroll
  for (int vt = 0; vt < 16; ++vt) {
    #pragma unroll
    for (int r = 0; r < 4; ++r) {
      int row = qt * 64 + w * 16 + g * 4 + r;
      int col = h * 256 + vt * 16 + c;
      outp[(size_t)row * 5120 + col] = f2bf(acc[vt][r] * inv[r]);
    }
  }
}

extern "C" void kernel_launch(void* const* d_in, const int* in_sizes, int n_in,
                              void* d_out, int out_size, void* d_ws, size_t ws_size,
                              hipStream_t stream) {
  const float* hidden = (const float*)d_in[0];
  const float* w_q_a  = (const float*)d_in[1];
  const float* w_q_b  = (const float*)d_in[2];
  const float* w_kv_a = (const float*)d_in[3];
  const float* w_kv_b = (const float*)d_in[4];
  const float* w_o    = (const float*)d_in[5];
  const float* g_q_a  = (const float*)d_in[6];
  const float* g_kv_a = (const float*)d_in[7];
  float* out = (float*)d_out;

  const int S = 2048;
  char* ws = (char*)d_ws;
  // overlay plan (bytes); peak 153.1 MB (< 158.3 MB proven in round 1)
  unsigned short* wo_t    = (unsigned short*)(ws + 0);          // [2048,5120] live S1-S12
  unsigned short* hid_bf  = (unsigned short*)(ws + 20971520);   // [2048,2048] S1-S5
  unsigned short* Kc      = (unsigned short*)(ws + 20971520);   // 21MB, written S10
  unsigned short* wqa_t   = (unsigned short*)(ws + 29360128);   // [768,2048] S1-S2
  unsigned short* wqb_t   = (unsigned short*)(ws + 32505856);   // [5120,768] S1-S4
  float*          wo_part = (float*)(ws + 20971520);            // 33.5MB, S12 only
  unsigned short* wkva_t  = (unsigned short*)(ws + 40370176);   // [576,2048] S1-S5
  unsigned short* wkvb_t  = (unsigned short*)(ws + 42729472);   // [8960,512] S1-S8
  unsigned short* q_c     = (unsigned short*)(ws + 51904512);   // [2048,768] S3-S4
  unsigned short* kv_c    = (unsigned short*)(ws + 55050240);   // [2048,512] S7-S8
  float*          ckv     = (float*)(ws + 57147392);            // [2048,576] S6-S10
  unsigned short* qbf     = (unsigned short*)(ws + 61865984);   // [2048,5120] S4-S9
  unsigned short* Vc      = (unsigned short*)(ws + 61865984);   // 21MB, written S10
  unsigned short* kvbf    = (unsigned short*)(ws + 82837504);   // [2048,8960] S8-S10
  unsigned short* attn_bf = (unsigned short*)(ws + 82837504);   // 21MB, written S11
  float*          qa_part = (float*)(ws + 119537664);           // 25.2MB S2-S3
  float*          kva_part= (float*)(ws + 119537664);           // 18.9MB S5-S6
  unsigned short* Qc      = (unsigned short*)(ws + 119537664);  // 21MB, written S9

  dim3 blk(256);
  dim3 tblk(32, 8);

  // S1: conversions / transposes
  f32_to_bf16_kernel<<<2048, blk, 0, stream>>>(hidden, hid_bf, S * 2048 / 8);
  transpose_f32_bf16<<<dim3(768 / 32, 2048 / 32), tblk, 0, stream>>>(w_q_a, wqa_t, 2048, 768);
  transpose_f32_bf16<<<dim3(5120 / 32, 768 / 32), tblk, 0, stream>>>(w_q_b, wqb_t, 768, 5120);
  transpose_f32_bf16<<<dim3(576 / 32, 2048 / 32), tblk, 0, stream>>>(w_kv_a, wkva_t, 2048, 576);
  transpose_f32_bf16<<<dim3(8960 / 32, 512 / 32), tblk, 0, stream>>>(w_kv_b, wkvb_t, 512, 8960);
  transpose_f32_bf16<<<dim3(2048 / 32, 5120 / 32), tblk, 0, stream>>>(w_o, wo_t, 5120, 2048);

  // S2-S4: q path (split-K 4 on q_a, fused reduce+rmsnorm)
  gemm_mfma<0><<<dim3(6, 16, 4), blk, 0, stream>>>(hid_bf, wqa_t, qa_part, S, 768, 2048, 512);
  rmsnorm4_kernel<<<S, blk, 0, stream>>>(qa_part, g_q_a, q_c, (size_t)S * 768);
  gemm_mfma<1><<<dim3(40, 16, 1), blk, 0, stream>>>(q_c, wqb_t, qbf, S, 5120, 768, 768);

  // S5-S8: kv path (split-K 4 on kv_a)
  gemm_mfma<0><<<dim3(5, 16, 4), blk, 0, stream>>>(hid_bf, wkva_t, kva_part, S, 576, 2048, 512);
  reduce_add_kernel<<<(S * 576 / 4 + 255) / 256, blk, 0, stream>>>(
      kva_part, ckv, S * 576 / 4, 4, (size_t)S * 576 / 4);
  rmsnorm_kernel<<<S, blk, 0, stream>>>(ckv, g_kv_a, kv_c, 512, 576, 512);
  gemm_mfma<1><<<dim3(70, 16, 1), blk, 0, stream>>>(kv_c, wkvb_t, kvbf, S, 8960, 512, 512);

  // S9-S11: attention
  pack_q<<<dim3(128, NHEADS), blk, 0, stream>>>(qbf, Qc);
  pack_kv<<<dim3(64, NHEADS), blk, 0, stream>>>(kvbf, ckv, Kc, Vc);
  attn_mfma<<<dim3(32, NHEADS), blk, 0, stream>>>(Qc, Kc, Vc, attn_bf);

  // S12: output projection (split-K 2) + reduce
  gemm_mfma<0><<<dim3(16, 16, 2), blk, 0, stream>>>(attn_bf, wo_t, wo_part, S, 2048, 5120, 2560);
  reduce_add_kernel<<<(S * 2048 / 4 + 255) / 256, blk, 0, stream>>>(
      wo_part, out, S * 2048 / 4, 2, (size_t)S * 2048 / 4);
}

// Round 5
// 423.417 us; speedup vs baseline: 8.9472x; 1.3832x over previous
//
#include <hip/hip_runtime.h>
#include <hip/hip_bf16.h>
#include <math.h>

#define NHEADS 20

typedef short bf16x8 __attribute__((ext_vector_type(8)));
typedef float f32x4 __attribute__((ext_vector_type(4)));

__device__ inline float bf2f(unsigned short u) {
  union { unsigned int i; float f; } x; x.i = ((unsigned int)u) << 16; return x.f;
}
__device__ inline unsigned short f2bf(float f) {
  __hip_bfloat16 h = __float2bfloat16(f);
  union { __hip_bfloat16 h; unsigned short u; } x; x.h = h; return x.u;
}
__device__ inline unsigned int pk2(float a, float b) {
  return (unsigned int)f2bf(a) | ((unsigned int)f2bf(b) << 16);
}
__device__ inline void gload_lds16(const void* g, void* l) {
  __builtin_amdgcn_global_load_lds(
      (const __attribute__((address_space(1))) void*)g,
      (__attribute__((address_space(3))) void*)l, 16, 0, 0);
}

// ---------------- fp32 -> bf16 copy (8 elems/thread) ------------------------
__global__ __launch_bounds__(256) void f32_to_bf16_kernel(
    const float* __restrict__ in, unsigned short* __restrict__ out, int n8) {
  int idx = blockIdx.x * 256 + threadIdx.x;
  if (idx < n8) {
    float4 a = reinterpret_cast<const float4*>(in)[idx * 2];
    float4 b = reinterpret_cast<const float4*>(in)[idx * 2 + 1];
    union { unsigned short u[8]; uint4 v; } o;
    o.u[0] = f2bf(a.x); o.u[1] = f2bf(a.y); o.u[2] = f2bf(a.z); o.u[3] = f2bf(a.w);
    o.u[4] = f2bf(b.x); o.u[5] = f2bf(b.y); o.u[6] = f2bf(b.z); o.u[7] = f2bf(b.w);
    reinterpret_cast<uint4*>(out)[idx] = o.v;
  }
}

// ---------------- zero a u32 (task-queue counter) ---------------------------
__global__ void zero_u32(unsigned int* p) { if (threadIdx.x == 0) *p = 0u; }

// ---------------- fp32 [R,C] -> bf16 transposed [C,R] -----------------------
__global__ __launch_bounds__(256) void transpose_f32_bf16(
    const float* __restrict__ in, unsigned short* __restrict__ out, int R, int C0) {
  __shared__ float tile[32][33];
  const int tx = threadIdx.x, ty = threadIdx.y;
  const int bc = blockIdx.x * 32, br = blockIdx.y * 32;
  #pragma unroll
  for (int j = 0; j < 4; ++j)
    tile[ty + 8 * j][tx] = in[(size_t)(br + ty + 8 * j) * C0 + bc + tx];
  __syncthreads();
  #pragma unroll
  for (int j = 0; j < 4; ++j)
    out[(size_t)(bc + ty + 8 * j) * R + br + tx] = f2bf(tile[tx][ty + 8 * j]);
}

// ---------------- elementwise multi-part reduce (float4) --------------------
__global__ __launch_bounds__(256) void reduce_add_kernel(
    const float* __restrict__ in, float* __restrict__ out, int n4, int parts, size_t stride4) {
  int idx = blockIdx.x * 256 + threadIdx.x;
  if (idx < n4) {
    const float4* in4 = reinterpret_cast<const float4*>(in);
    float4 s = in4[idx];
    for (int p = 1; p < parts; ++p) {
      float4 b = in4[idx + p * stride4];
      s.x += b.x; s.y += b.y; s.z += b.z; s.w += b.w;
    }
    reinterpret_cast<float4*>(out)[idx] = s;
  }
}

// ---------------- bf16 MFMA GEMM, 2-phase dbuf, optional split-K ------------
template <int BF16OUT>
__global__ __launch_bounds__(256) void gemm_mfma(
    const unsigned short* __restrict__ A, const unsigned short* __restrict__ Bt,
    void* __restrict__ Cout, int M, int N, int K, int ksize) {
  __shared__ unsigned short As[2][4096] __attribute__((aligned(16)));
  __shared__ unsigned short Bs[2][4096] __attribute__((aligned(16)));
  const int t = threadIdx.x;
  const int l = t & 63;
  const int w = t >> 6;
  const int bm = blockIdx.y * 128;
  const int bn = blockIdx.x * 128;
  const int kbase = blockIdx.z * ksize;
  const int wr = w >> 1, wc = w & 1;
  const int lr = l & 15, lk = (l >> 4) * 8;

  f32x4 acc[4][4];
  #pragma unroll
  for (int i = 0; i < 4; ++i)
    #pragma unroll
    for (int j = 0; j < 4; ++j) acc[i][j] = (f32x4){0.f, 0.f, 0.f, 0.f};

  int arow0 = bm + (w + 0) * 16 + lr;
  int arow1 = bm + (w + 4) * 16 + lr;
  int bcol0 = bn + (w + 0) * 16 + lr; if (bcol0 >= N) bcol0 = N - 1;
  int bcol1 = bn + (w + 4) * 16 + lr; if (bcol1 >= N) bcol1 = N - 1;
  const unsigned short* aptr0 = A + (size_t)arow0 * K + kbase + lk;
  const unsigned short* aptr1 = A + (size_t)arow1 * K + kbase + lk;
  const unsigned short* bptr0 = Bt + (size_t)bcol0 * K + kbase + lk;
  const unsigned short* bptr1 = Bt + (size_t)bcol1 * K + kbase + lk;

#define GEMM_STAGE(buf, koff)                                  \
  gload_lds16(aptr0 + (koff), &As[buf][(w + 0) * 512]);        \
  gload_lds16(aptr1 + (koff), &As[buf][(w + 4) * 512]);        \
  gload_lds16(bptr0 + (koff), &Bs[buf][(w + 0) * 512]);        \
  gload_lds16(bptr1 + (koff), &Bs[buf][(w + 4) * 512]);

  GEMM_STAGE(0, 0)
  int cur = 0;
  for (int k0 = 0; k0 < ksize; k0 += 32) {
    if (k0 + 32 < ksize) {
      GEMM_STAGE(cur ^ 1, k0 + 32)
      asm volatile("s_waitcnt vmcnt(4)" ::: "memory");
    } else {
      asm volatile("s_waitcnt vmcnt(0)" ::: "memory");
    }
    __builtin_amdgcn_s_barrier();
    bf16x8 af[4], bfr[4];
    #pragma unroll
    for (int mi = 0; mi < 4; ++mi)
      af[mi] = *reinterpret_cast<const bf16x8*>(&As[cur][(wr * 4 + mi) * 512 + l * 8]);
    #pragma unroll
    for (int nj = 0; nj < 4; ++nj)
      bfr[nj] = *reinterpret_cast<const bf16x8*>(&Bs[cur][(wc * 4 + nj) * 512 + l * 8]);
    #pragma unroll
    for (int mi = 0; mi < 4; ++mi)
      #pragma unroll
      for (int nj = 0; nj < 4; ++nj)
        acc[mi][nj] = __builtin_amdgcn_mfma_f32_16x16x32_bf16(af[mi], bfr[nj], acc[mi][nj], 0, 0, 0);
    __builtin_amdgcn_s_barrier();
    cur ^= 1;
  }
#undef GEMM_STAGE

  const bool split = (gridDim.z > 1);
  float* cf = (float*)Cout + (split ? (size_t)blockIdx.z * M * N : 0);
  #pragma unroll
  for (int mi = 0; mi < 4; ++mi) {
    #pragma unroll
    for (int nj = 0; nj < 4; ++nj) {
      int col = bn + wc * 64 + nj * 16 + lr;
      if (col < N) {
        #pragma unroll
        for (int r = 0; r < 4; ++r) {
          int row = bm + wr * 64 + mi * 16 + (l >> 4) * 4 + r;
          if (!split && BF16OUT)
            ((unsigned short*)Cout)[(size_t)row * N + col] = f2bf(acc[mi][nj][r]);
          else
            cf[(size_t)row * N + col] = acc[mi][nj][r];
        }
      }
    }
  }
}

// ---------------- RMSNorm (fp32 in, bf16 out) -------------------------------
__global__ __launch_bounds__(256) void rmsnorm_kernel(
    const float* __restrict__ in, const float* __restrict__ g, unsigned short* __restrict__ out,
    int N, int in_stride, int out_stride) {
  __shared__ float red[256];
  const int row = blockIdx.x, t = threadIdx.x;
  const float* x = in + (size_t)row * in_stride;
  float s = 0.f;
  for (int i = t; i < N; i += 256) { float v = x[i]; s += v * v; }
  red[t] = s;
  __syncthreads();
  for (int o = 128; o > 0; o >>= 1) {
    if (t < o) red[t] += red[t + o];
    __syncthreads();
  }
  const float scale = rsqrtf(red[0] / (float)N + 1e-6f);
  unsigned short* y = out + (size_t)row * out_stride;
  for (int i = t; i < N; i += 256) y[i] = f2bf(x[i] * scale * g[i]);
}

// ---------------- fused 4-part reduce + RMSNorm (N=768) ---------------------
__global__ __launch_bounds__(256) void rmsnorm4_kernel(
    const float* __restrict__ parts, const float* __restrict__ g,
    unsigned short* __restrict__ out, size_t pstride) {
  __shared__ float red[256];
  const int row = blockIdx.x, t = threadIdx.x;
  const float* x = parts + (size_t)row * 768;
  float v[3];
  float s = 0.f;
  #pragma unroll
  for (int e = 0; e < 3; ++e) {
    int i = t + 256 * e;
    float a = x[i] + x[i + pstride] + x[i + 2 * pstride] + x[i + 3 * pstride];
    v[e] = a;
    s += a * a;
  }
  red[t] = s;
  __syncthreads();
  for (int o = 128; o > 0; o >>= 1) {
    if (t < o) red[t] += red[t + o];
    __syncthreads();
  }
  const float scale = rsqrtf(red[0] / 768.f + 1e-6f);
  unsigned short* y = out + (size_t)row * 768;
  #pragma unroll
  for (int e = 0; e < 3; ++e) {
    int i = t + 256 * e;
    y[i] = f2bf(v[e] * scale * g[i]);
  }
}

// ---------------- pack Q (rope fused) ---------------------------------------
__global__ __launch_bounds__(256) void pack_q(
    const unsigned short* __restrict__ qbf, unsigned short* __restrict__ Qc) {
  const int qsub = blockIdx.x;   // 0..127
  const int h = blockIdx.y;
  unsigned short* dst = Qc + ((size_t)(h * 128 + qsub)) * 4096;
  const int t = threadIdx.x;
  #pragma unroll
  for (int j = 0; j < 2; ++j) {
    int s = t + 256 * j;
    int g8 = s >> 4, row = s & 15;
    int qrow = qsub * 16 + row;
    const unsigned short* src = qbf + (size_t)qrow * 5120 + h * 256 + g8 * 8;
    union { unsigned short u[8]; uint4 v; } o;
    if (g8 < 24) {
      o.v = *reinterpret_cast<const uint4*>(src);
    } else {
      const unsigned short* part = qbf + (size_t)qrow * 5120 + h * 256 + (g8 ^ 4) * 8;
      float pos = (float)qrow;
      #pragma unroll
      for (int e = 0; e < 8; ++e) {
        int i = g8 * 8 - 192 + e;
        int fi = i & 31;
        float ang = pos * exp2f(-(float)fi * 0.622861517f);
        float cs = cosf(ang), sn = sinf(ang);
        float own = bf2f(src[e]);
        float other = bf2f(part[e]);
        float val = (i < 32) ? (own * cs - other * sn) : (own * cs + other * sn);
        o.u[e] = f2bf(val);
      }
    }
    *reinterpret_cast<uint4*>(dst + s * 8) = o.v;
  }
}

// ---------------- pack K,V ---------------------------------------------------
__global__ __launch_bounds__(256) void pack_kv(
    const unsigned short* __restrict__ kvbf, const float* __restrict__ ckv,
    unsigned short* __restrict__ Kc, unsigned short* __restrict__ Vc) {
  const int kt = blockIdx.x;   // 0..63
  const int h = blockIdx.y;
  const int t = threadIdx.x;
  unsigned short* kdst = Kc + ((size_t)(h * 64 + kt)) * 8192;
  unsigned short* vdst = Vc + ((size_t)(h * 64 + kt)) * 8192;
  #pragma unroll
  for (int j = 0; j < 4; ++j) {
    int s = t + 256 * j;
    int sub = s >> 9, g8 = (s >> 4) & 31, row = s & 15;
    int krow = kt * 32 + sub * 16 + row;
    union { unsigned short u[8]; uint4 v; } o;
    if (g8 < 24) {
      o.v = *reinterpret_cast<const uint4*>(kvbf + (size_t)krow * 8960 + h * 448 + g8 * 8);
    } else {
      const float* kr = ckv + (size_t)krow * 576 + 512;
      float pos = (float)krow;
      #pragma unroll
      for (int e = 0; e < 8; ++e) {
        int i = g8 * 8 - 192 + e;
        int fi = i & 31;
        float ang = pos * exp2f(-(float)fi * 0.622861517f);
        float cs = cosf(ang), sn = sinf(ang);
        float own = kr[i];
        float other = kr[i < 32 ? i + 32 : i - 32];
        float val = (i < 32) ? (own * cs - other * sn) : (own * cs + other * sn);
        o.u[e] = f2bf(val);
      }
    }
    *reinterpret_cast<uint4*>(kdst + s * 8) = o.v;
  }
  #pragma unroll
  for (int j = 0; j < 4; ++j) {
    int s = t + 256 * j;
    int vt = s >> 6, gg = (s >> 4) & 3, col = s & 15;
    union { unsigned short u[8]; uint4 v; } o;
    #pragma unroll
    for (int e = 0; e < 8; ++e) {
      int krow = kt * 32 + gg * 8 + e;
      o.u[e] = kvbf[(size_t)krow * 8960 + h * 448 + 192 + vt * 16 + col];
    }
    *reinterpret_cast<uint4*>(vdst + s * 8) = o.v;
  }
}

// ---------------- MFMA flash attention: persistent + task queue -------------
// Swapped operands: QK = mfma(K,Q) -> D[kpos][qrow], PV = mfma(V,P) ->
// D[vcol][qrow]. Lane (g,c) owns q-row c; softmax state fully lane-local,
// row-reduce = 2x shfl_xor(16,32). 768 persistent blocks, tasks (h,qt)
// grabbed biggest-first via atomic counter (outputs disjoint).
__global__ __launch_bounds__(256) void attn_mfma(
    const unsigned short* __restrict__ Qc, const unsigned short* __restrict__ Kc,
    const unsigned short* __restrict__ Vc, unsigned short* __restrict__ outp,
    unsigned int* __restrict__ qcounter) {
  __shared__ unsigned short Ks[8192] __attribute__((aligned(16)));
  __shared__ unsigned short Vs[8192] __attribute__((aligned(16)));
  __shared__ unsigned short Ps[2048] __attribute__((aligned(16)));
  __shared__ unsigned int task_s;
  const int t = threadIdx.x;
  const int l = t & 63;
  const int w = t >> 6;
  const int g = l >> 4;
  const int c = l & 15;

  for (;;) {
    __syncthreads();
    if (t == 0) task_s = atomicAdd(qcounter, 1u);
    __syncthreads();
    const unsigned int task = task_s;
    if (task >= 640u) break;
    const int qt = 31 - (int)(task / 20u);   // biggest tiles first
    const int h = (int)(task % 20u);

    const unsigned short* qtile = Qc + ((size_t)(h * 128 + qt * 4 + w)) * 4096;
    bf16x8 qf[8];
    #pragma unroll
    for (int st = 0; st < 8; ++st)
      qf[st] = *reinterpret_cast<const bf16x8*>(qtile + st * 512 + l * 8);

    f32x4 acc[16];
    #pragma unroll
    for (int vt = 0; vt < 16; ++vt) acc[vt] = (f32x4){0.f, 0.f, 0.f, 0.f};
    float m = -1e30f, lsum = 0.f;
    const int qpos = qt * 64 + w * 16 + c;

    const unsigned short* kbase_p = Kc + (size_t)h * 64 * 8192 + (w * 4) * 512 + l * 8;
    const unsigned short* vbase_p = Vc + (size_t)h * 64 * 8192 + (w * 4) * 512 + l * 8;

    const int niter = 2 * qt + 2;
    for (int kt = 0; kt < niter; ++kt) {
      __syncthreads();  // all waves done reading Ks/Vs of prev iter
      {
        const unsigned short* ks_ = kbase_p + (size_t)kt * 8192;
        const unsigned short* vs_ = vbase_p + (size_t)kt * 8192;
        #pragma unroll
        for (int j = 0; j < 4; ++j) {
          gload_lds16(ks_ + j * 512, &Ks[(w * 4 + j) * 512]);
          gload_lds16(vs_ + j * 512, &Vs[(w * 4 + j) * 512]);
        }
      }
      asm volatile("s_waitcnt vmcnt(0)" ::: "memory");
      __builtin_amdgcn_s_barrier();

      // QK^T swapped: s0/s1 rows = k-pos (g*4+r / 16+g*4+r), cols = q-row c
      f32x4 s0 = {0.f, 0.f, 0.f, 0.f}, s1 = {0.f, 0.f, 0.f, 0.f};
      #pragma unroll
      for (int st = 0; st < 8; ++st) {
        bf16x8 k0 = *reinterpret_cast<const bf16x8*>(&Ks[st * 512 + l * 8]);
        bf16x8 k1 = *reinterpret_cast<const bf16x8*>(&Ks[4096 + st * 512 + l * 8]);
        s0 = __builtin_amdgcn_mfma_f32_16x16x32_bf16(k0, qf[st], s0, 0, 0, 0);
        s1 = __builtin_amdgcn_mfma_f32_16x16x32_bf16(k1, qf[st], s1, 0, 0, 0);
      }

      float a0[4], a1[4];
      const bool masked = (kt >= 2 * qt);
      #pragma unroll
      for (int r = 0; r < 4; ++r) {
        a0[r] = s0[r] * 0.0625f;
        a1[r] = s1[r] * 0.0625f;
        if (masked) {
          if (kt * 32 + g * 4 + r > qpos) a0[r] = -1e30f;
          if (kt * 32 + 16 + g * 4 + r > qpos) a1[r] = -1e30f;
        }
      }
      float mx = fmaxf(fmaxf(fmaxf(a0[0], a0[1]), fmaxf(a0[2], a0[3])),
                       fmaxf(fmaxf(a1[0], a1[1]), fmaxf(a1[2], a1[3])));
      mx = fmaxf(mx, __shfl_xor(mx, 16));
      mx = fmaxf(mx, __shfl_xor(mx, 32));
      float rs;
      if (mx > m + 8.f) { rs = __expf(m - mx); m = mx; } else { rs = 1.f; }
      float e0[4], e1[4];
      float sum = 0.f;
      #pragma unroll
      for (int r = 0; r < 4; ++r) {
        e0[r] = __expf(a0[r] - m);
        e1[r] = __expf(a1[r] - m);
        sum += e0[r] + e1[r];
      }
      sum += __shfl_xor(sum, 16);
      sum += __shfl_xor(sum, 32);
      lsum = lsum * rs + sum;

      // P -> Ps in A-frag layout: elem addr (k>>3)*128 + c*8 + (k&7)
      const int pbase = w * 512 + (g >> 1) * 128 + c * 8 + (g & 1) * 4;
      uint2 pw0, pw1;
      pw0.x = pk2(e0[0], e0[1]); pw0.y = pk2(e0[2], e0[3]);
      pw1.x = pk2(e1[0], e1[1]); pw1.y = pk2(e1[2], e1[3]);
      *reinterpret_cast<uint2*>(&Ps[pbase]) = pw0;
      *reinterpret_cast<uint2*>(&Ps[pbase + 256]) = pw1;

      if (rs != 1.f) {
        #pragma unroll
        for (int vt = 0; vt < 16; ++vt) {
          acc[vt][0] *= rs; acc[vt][1] *= rs; acc[vt][2] *= rs; acc[vt][3] *= rs;
        }
      }

      // PV swapped: acc[vt] rows = v-col (vt*16 + g*4 + r), cols = q-row c
      bf16x8 pa = *reinterpret_cast<const bf16x8*>(&Ps[w * 512 + l * 8]);
      #pragma unroll
      for (int vt = 0; vt < 16; ++vt) {
        bf16x8 vb = *reinterpret_cast<const bf16x8*>(&Vs[vt * 512 + l * 8]);
        acc[vt] = __builtin_amdgcn_mfma_f32_16x16x32_bf16(vb, pa, acc[vt], 0, 0, 0);
      }
    }

    const float inv = 1.f / lsum;
    const int row = qt * 64 + w * 16 + c;
    unsigned short* orow = outp + (size_t)row * 5120 + h * 256 + g * 4;
    #pragma unroll
    for (int vt = 0; vt < 16; ++vt) {
      uint2 o;
      o.x = pk2(acc[vt][0] * inv, acc[vt][1] * inv);
      o.y = pk2(acc[vt][2] * inv, acc[vt][3] * inv);
      *reinterpret_cast<uint2*>(orow + vt * 16) = o;
    }
  }
}

extern "C" void kernel_launch(void* const* d_in, const int* in_sizes, int n_in,
                              void* d_out, int out_size, void* d_ws, size_t ws_size,
                              hipStream_t stream) {
  const float* hidden = (const float*)d_in[0];
  const float* w_q_a  = (const float*)d_in[1];
  const float* w_q_b  = (const float*)d_in[2];
  const float* w_kv_a = (const float*)d_in[3];
  const float* w_kv_b = (const float*)d_in[4];
  const float* w_o    = (const float*)d_in[5];
  const float* g_q_a  = (const float*)d_in[6];
  const float* g_kv_a = (const float*)d_in[7];
  float* out = (float*)d_out;

  const int S = 2048;
  char* ws = (char*)d_ws;
  // overlay plan (bytes); peak ~153.1 MB (< 157.9 MB proven in round 1)
  unsigned short* wo_t    = (unsigned short*)(ws + 0);          // [2048,5120] live S1-S12
  unsigned short* hid_bf  = (unsigned short*)(ws + 20971520);   // [2048,2048] S1-S5
  unsigned short* Kc      = (unsigned short*)(ws + 20971520);   // 21MB, written S10
  unsigned short* wqa_t   = (unsigned short*)(ws + 29360128);   // [768,2048] S1-S2
  unsigned short* wqb_t   = (unsigned short*)(ws + 32505856);   // [5120,768] S1-S4
  float*          wo_part = (float*)(ws + 20971520);            // 33.5MB, S12 only
  unsigned short* wkva_t  = (unsigned short*)(ws + 40370176);   // [576,2048] S1-S5
  unsigned short* wkvb_t  = (unsigned short*)(ws + 42729472);   // [8960,512] S1-S8
  unsigned short* q_c     = (unsigned short*)(ws + 51904512);   // [2048,768] S3-S4
  unsigned short* kv_c    = (unsigned short*)(ws + 55050240);   // [2048,512] S7-S8
  float*          ckv     = (float*)(ws + 57147392);            // [2048,576] S6-S10
  unsigned short* qbf     = (unsigned short*)(ws + 61865984);   // [2048,5120] S4-S9
  unsigned short* Vc      = (unsigned short*)(ws + 61865984);   // 21MB, written S10
  unsigned short* kvbf    = (unsigned short*)(ws + 82837504);   // [2048,8960] S8-S10
  unsigned short* attn_bf = (unsigned short*)(ws + 82837504);   // 21MB, written S11
  float*          qa_part = (float*)(ws + 119537664);           // 25.2MB S2-S3
  float*          kva_part= (float*)(ws + 119537664);           // 18.9MB S5-S6
  unsigned short* Qc      = (unsigned short*)(ws + 119537664);  // 21MB, written S9
  unsigned int*   qcnt    = (unsigned int*)(ws + 150000000);    // 4B, S11 only

  dim3 blk(256);
  dim3 tblk(32, 8);

  // S1: conversions / transposes
  f32_to_bf16_kernel<<<2048, blk, 0, stream>>>(hidden, hid_bf, S * 2048 / 8);
  transpose_f32_bf16<<<dim3(768 / 32, 2048 / 32), tblk, 0, stream>>>(w_q_a, wqa_t, 2048, 768);
  transpose_f32_bf16<<<dim3(5120 / 32, 768 / 32), tblk, 0, stream>>>(w_q_b, wqb_t, 768, 5120);
  transpose_f32_bf16<<<dim3(576 / 32, 2048 / 32), tblk, 0, stream>>>(w_kv_a, wkva_t, 2048, 576);
  transpose_f32_bf16<<<dim3(8960 / 32, 512 / 32), tblk, 0, stream>>>(w_kv_b, wkvb_t, 512, 8960);
  transpose_f32_bf16<<<dim3(2048 / 32, 5120 / 32), tblk, 0, stream>>>(w_o, wo_t, 5120, 2048);

  // S2-S4: q path (split-K 4 on q_a, fused reduce+rmsnorm)
  gemm_mfma<0><<<dim3(6, 16, 4), blk, 0, stream>>>(hid_bf, wqa_t, qa_part, S, 768, 2048, 512);
  rmsnorm4_kernel<<<S, blk, 0, stream>>>(qa_part, g_q_a, q_c, (size_t)S * 768);
  gemm_mfma<1><<<dim3(40, 16, 1), blk, 0, stream>>>(q_c, wqb_t, qbf, S, 5120, 768, 768);

  // S5-S8: kv path (split-K 4 on kv_a)
  gemm_mfma<0><<<dim3(5, 16, 4), blk, 0, stream>>>(hid_bf, wkva_t, kva_part, S, 576, 2048, 512);
  reduce_add_kernel<<<(S * 576 / 4 + 255) / 256, blk, 0, stream>>>(
      kva_part, ckv, S * 576 / 4, 4, (size_t)S * 576 / 4);
  rmsnorm_kernel<<<S, blk, 0, stream>>>(ckv, g_kv_a, kv_c, 512, 576, 512);
  gemm_mfma<1><<<dim3(70, 16, 1), blk, 0, stream>>>(kv_c, wkvb_t, kvbf, S, 8960, 512, 512);

  // S9-S11: attention (persistent, task queue)
  pack_q<<<dim3(128, NHEADS), blk, 0, stream>>>(qbf, Qc);
  pack_kv<<<dim3(64, NHEADS), blk, 0, stream>>>(kvbf, ckv, Kc, Vc);
  zero_u32<<<1, 64, 0, stream>>>(qcnt);
  attn_mfma<<<768, blk, 0, stream>>>(Qc, Kc, Vc, attn_bf, qcnt);

  // S12: output projection (split-K 2) + reduce
  gemm_mfma<0><<<dim3(16, 16, 2), blk, 0, stream>>>(attn_bf, wo_t, wo_part, S, 2048, 5120, 2560);
  reduce_add_kernel<<<(S * 2048 / 4 + 255) / 256, blk, 0, stream>>>(
      wo_part, out, S * 2048 / 4, 2, (size_t)S * 2048 / 4);
}